// Round 2
// baseline (3180.764 us; speedup 1.0000x reference)
//
#include <hip/hip_runtime.h>
#include <cstdint>
#include <cstddef>
#include <cstdio>

// ---------------------------------------------------------------------------
// SpaceFormerImputation on MI355X (gfx950).
// Round-2 theory: inputs/outputs are fp32 (reference-literal). Output-0 NaN in
// round 1 proved x is NOT bf16 (a bf16 gather can't mint NaN; f32 halves can).
// To be robust, the kernel sniffs dtypes at runtime (device-side flags):
//   flags[0] = mask fmt: 0=i32, 1=u8, 2=bf16, 3=f32
//   flags[1] = drop_idx is int64
//   flags[2] = float world is f32 (1) or bf16 (0)
// Internally everything is bf16 (MFMA); boundaries convert per flags.
// ---------------------------------------------------------------------------

typedef unsigned short u16;
typedef __bf16 bf16x8 __attribute__((ext_vector_type(8)));
typedef float f32x4 __attribute__((ext_vector_type(4)));

#define GAMMA_C 0.5f
#define NEG_C   (-1e9f)
#define SCALE_C 0.04419417382415922f   // 1/sqrt(512)
#define NG      (8192 * 102)

__device__ __forceinline__ float b2f(u16 u) {
  union { unsigned int i; float f; } c; c.i = ((unsigned int)u) << 16; return c.f;
}
__device__ __forceinline__ u16 f2b(float f) {
  union { float f; unsigned int i; } c; c.f = f;
  unsigned int u = c.i + 0x7FFFu + ((c.i >> 16) & 1u);
  return (u16)(u >> 16);
}
__device__ __forceinline__ float gelu_exact(float x) {
  return 0.5f * x * (1.0f + erff(x * 0.70710678118654752f));
}
__device__ __forceinline__ bool mask_at(const void* m, size_t i, int f) {
  if (f == 1) return ((const unsigned char*)m)[i] != 0;
  if (f == 0) return ((const int*)m)[i] != 0;
  if (f == 2) return ((const u16*)m)[i] != 0;
  return ((const float*)m)[i] != 0.0f;
}
__device__ __forceinline__ int idx_at(const void* p, int i, int i64) {
  return i64 ? (int)((const long long*)p)[i] : ((const int*)p)[i];
}
__device__ __forceinline__ float fl_at(const void* p, size_t i, int f32m) {
  return f32m ? ((const float*)p)[i] : b2f(((const u16*)p)[i]);
}

#define GLD16(g, l) __builtin_amdgcn_global_load_lds(                         \
    (const __attribute__((address_space(1))) void*)(g),                       \
    (__attribute__((address_space(3))) void*)(l), 16, 0, 0)

// ----------------------------- dtype sniffing ------------------------------
__global__ void detect_all(const unsigned char* __restrict__ rmask,
                           const void* __restrict__ xin,
                           const void* __restrict__ idx,
                           int* __restrict__ flags) {
  __shared__ int nz[4];
  __shared__ int mx, bl;
  const int t = threadIdx.x;
  if (t < 4) nz[t] = 0;
  if (t == 0) { mx = 0; bl = 0; }
  __syncthreads();
  // mask byte-pattern over first 4 KiB (stride 256 preserves i&3 classes)
  int cnt = 0, lm = 0;
  for (int i = t; i < 4096; i += 256) {
    const int v = rmask[i];
    if (v) { ++cnt; if (v > lm) lm = v; }
  }
  if (cnt) atomicAdd(&nz[t & 3], cnt);
  if (lm) atomicMax(&mx, lm);
  // x float-world sniff: even u16s of first 8 KiB. bf16 world: exponent field
  // concentrated near 127; f32 world: these are mantissa-low halves (uniform).
  int bcnt = 0;
  for (int i = t; i < 2048; i += 256) {
    const u16 u = ((const u16*)xin)[2 * i];
    const int e = (u >> 7) & 0xFF;
    if ((e >= 110 && e <= 141) || u == 0) ++bcnt;
  }
  atomicAdd(&bl, bcnt);
  __syncthreads();
  if (t == 0) {
    int f;
    if (nz[1] == 0 && nz[2] == 0 && nz[3] == 0) f = 0;
    else if (nz[0] == 0 && nz[1] == 0) f = 3;
    else if (mx <= 1) f = 1;
    else f = 2;
    flags[0] = f;
    flags[2] = (bl >= 1536) ? 0 : 1;   // >=75% bf16-like -> bf16 world
    // drop_idx: first row is 102 sorted distinct ints in [0,512). int64 read
    // as int32 gives v,0,v,0,... which breaks strict ascent.
    int ok = 1, prev = -1;
    for (int j = 0; j < 102; ++j) {
      const int v = ((const int*)idx)[j];
      if (v <= prev || v < 0 || v >= 512) { ok = 0; break; }
      prev = v;
    }
    flags[1] = ok ? 0 : 1;
  }
}

// ---------------------- transpose + convert to bf16 ------------------------
__global__ void transpose_cvt(const void* __restrict__ in, u16* __restrict__ out,
                              int R, int C, const int* __restrict__ flags) {
  __shared__ u16 tile[32][33];
  const int f32m = flags[2];
  const int c0 = blockIdx.x * 32, r0 = blockIdx.y * 32;
  const int tx = threadIdx.x, ty = threadIdx.y;   // (32,8)
  for (int i = ty; i < 32; i += 8) {
    const size_t src = (size_t)(r0 + i) * C + (c0 + tx);
    tile[i][tx] = f32m ? f2b(((const float*)in)[src]) : ((const u16*)in)[src];
  }
  __syncthreads();
  for (int i = ty; i < 32; i += 8)
    out[(size_t)(c0 + i) * R + (r0 + tx)] = tile[tx][i];
}

// ------------------------------ small utils --------------------------------
__global__ void cvt_to_bf16(const void* __restrict__ in, u16* __restrict__ out,
                            int n, const int* __restrict__ flags) {
  const int i = blockIdx.x * blockDim.x + threadIdx.x;
  if (i < n)
    out[i] = flags[2] ? f2b(((const float*)in)[i]) : ((const u16*)in)[i];
}
__global__ void zero_drop(u16* __restrict__ dx, const void* __restrict__ idx,
                          const int* __restrict__ flags) {
  const int i = blockIdx.x * blockDim.x + threadIdx.x;
  if (i < NG) {
    const int row = i / 102;
    dx[(size_t)row * 512 + idx_at(idx, i, flags[1])] = 0;
  }
}
__global__ void gather_out_k(const void* __restrict__ x, const u16* __restrict__ h,
                             const void* __restrict__ idx, void* __restrict__ out,
                             const int* __restrict__ flags) {
  const int i = blockIdx.x * blockDim.x + threadIdx.x;
  if (i < NG) {
    const int row = i / 102;
    const int c = idx_at(idx, i, flags[1]);
    const size_t src = (size_t)row * 512 + c;
    if (flags[2]) {
      ((float*)out)[i] = ((const float*)x)[src];
      ((float*)out)[NG + i] = b2f(h[src]);
    } else {
      ((u16*)out)[i] = ((const u16*)x)[src];
      ((u16*)out)[NG + i] = h[src];
    }
  }
}

// ------------------------------ GEMM (B^T) ---------------------------------
// C[M,Nn] = A[M,K] @ Bt[Nn,K]^T, bf16 in, 128x128 tile, BK=64, 2x2 waves,
// 16x16x32 MFMA, XOR-swizzled LDS. act: 0=plain(+bias), 1=gelu(+bias),
// 2=store C transposed (ld=trld). mask!=null => score mode (scale+mask).
__global__ __launch_bounds__(256)
void gemm_bt(const u16* __restrict__ A, const u16* __restrict__ Bt,
             u16* __restrict__ C, int M, int Nn, int K,
             const void* __restrict__ bias, int act,
             const void* __restrict__ mask, const int* __restrict__ flags,
             long long mrow0, int trld) {
  __shared__ alignas(16) u16 As[128][64];
  __shared__ alignas(16) u16 Bs[128][64];
  const int tid = threadIdx.x;
  const int lane = tid & 63, wave = tid >> 6;
  const int l15 = lane & 15, l4 = lane >> 4;
  const int wm = (wave >> 1) << 6, wn = (wave & 1) << 6;
  const int m0 = blockIdx.y << 7, n0 = blockIdx.x << 7;

  f32x4 acc[4][4];
#pragma unroll
  for (int i = 0; i < 4; ++i)
#pragma unroll
    for (int j = 0; j < 4; ++j) acc[i][j] = (f32x4){0.f, 0.f, 0.f, 0.f};

  const int lrow = lane >> 3;
  const int lcg = (lane & 7) ^ lrow;
  const u16* aG = A + (size_t)(m0 + wave * 8 + lrow) * K + lcg * 8;
  const u16* bG = Bt + (size_t)(n0 + wave * 8 + lrow) * K + lcg * 8;
  u16* asDst = &As[wave * 8][0];
  u16* bsDst = &Bs[wave * 8][0];
  const int swz = (l15 & 7) << 3;

  for (int k0 = 0; k0 < K; k0 += 64) {
#pragma unroll
    for (int r = 0; r < 4; ++r) {
      GLD16(aG + (size_t)(r * 32) * K + k0, asDst + r * 32 * 64);
      GLD16(bG + (size_t)(r * 32) * K + k0, bsDst + r * 32 * 64);
    }
    __syncthreads();
#pragma unroll
    for (int kk = 0; kk < 2; ++kk) {
      bf16x8 a[4], b[4];
      const int koff = (((kk << 2) + l4) << 3) ^ swz;
#pragma unroll
      for (int i = 0; i < 4; ++i) {
        a[i] = *(const bf16x8*)&As[wm + (i << 4) + l15][koff];
        b[i] = *(const bf16x8*)&Bs[wn + (i << 4) + l15][koff];
      }
#pragma unroll
      for (int i = 0; i < 4; ++i)
#pragma unroll
        for (int j = 0; j < 4; ++j)
          acc[i][j] = __builtin_amdgcn_mfma_f32_16x16x32_bf16(a[i], b[j], acc[i][j], 0, 0, 0);
    }
    __syncthreads();
  }

  const int f32m = flags[2];
  const int mf = (mask != nullptr) ? flags[0] : 0;
#pragma unroll
  for (int i = 0; i < 4; ++i) {
    const int rbase = m0 + wm + (i << 4) + l4 * 4;   // C/D: row=(lane>>4)*4+reg
#pragma unroll
    for (int j = 0; j < 4; ++j) {
      const int gn = n0 + wn + (j << 4) + l15;       // C/D: col=lane&15
      if (act == 2) {                                // transposed store (V^T)
        ushort4 pk;
        pk.x = f2b(acc[i][j][0]); pk.y = f2b(acc[i][j][1]);
        pk.z = f2b(acc[i][j][2]); pk.w = f2b(acc[i][j][3]);
        *(ushort4*)&C[(size_t)gn * trld + rbase] = pk;
        continue;
      }
      float bv = 0.f;
      if (bias) bv = fl_at(bias, gn, f32m);
#pragma unroll
      for (int r = 0; r < 4; ++r) {
        const int gm = rbase + r;
        float v = acc[i][j][r] + bv;
        if (act == 1) v = gelu_exact(v);
        if (mask) {
          v *= SCALE_C;
          if (mask_at(mask, (size_t)(mrow0 + gm) * 8192 + gn, mf)) v = NEG_C;
        }
        C[(size_t)gm * Nn + gn] = f2b(v);
      }
    }
  }
}

// ------------------------------- PV GEMM -----------------------------------
// Out[q,d] = (sum_j w(q,j) * V[j,d]) / l[q],  w = exp(sr-m) + gamma*exp(sf-m)
__global__ __launch_bounds__(256)
void gemm_pv(const u16* __restrict__ sr, const u16* __restrict__ sf,
             const u16* __restrict__ Vt, u16* __restrict__ Out,
             const float* __restrict__ mvec, const float* __restrict__ lvec,
             int row0) {
  __shared__ alignas(16) u16 As[128][64];
  __shared__ alignas(16) u16 Bs[128][64];
  const int tid = threadIdx.x;
  const int lane = tid & 63, wave = tid >> 6;
  const int l15 = lane & 15, l4 = lane >> 4;
  const int wm = (wave >> 1) << 6, wn = (wave & 1) << 6;
  const int m0 = blockIdx.y << 7, n0 = blockIdx.x << 7;

  f32x4 acc[4][4];
#pragma unroll
  for (int i = 0; i < 4; ++i)
#pragma unroll
    for (int j = 0; j < 4; ++j) acc[i][j] = (f32x4){0.f, 0.f, 0.f, 0.f};

  const int lrow = lane >> 3;
  const int lcg = (lane & 7) ^ lrow;
  const u16* bG = Vt + (size_t)(n0 + wave * 8 + lrow) * 8192 + lcg * 8;
  u16* bsDst = &Bs[wave * 8][0];
  const int srow = tid >> 3;
  const int ssg = tid & 7;
  const int scg = ssg ^ (srow & 7);
  const int swz = (l15 & 7) << 3;

  for (int k0 = 0; k0 < 8192; k0 += 64) {
#pragma unroll
    for (int r = 0; r < 4; ++r)
      GLD16(bG + (size_t)(r * 32) * 8192 + k0, bsDst + r * 32 * 64);
#pragma unroll
    for (int it = 0; it < 4; ++it) {
      const int row = it * 32 + srow;
      const size_t off = (size_t)(m0 + row) * 8192 + k0 + scg * 8;
      const uint4 rv = *(const uint4*)(sr + off);
      const uint4 fv = *(const uint4*)(sf + off);
      const float mrow = mvec[row0 + m0 + row];
      const u16* r8 = (const u16*)&rv;
      const u16* f8 = (const u16*)&fv;
      u16 w8[8];
#pragma unroll
      for (int j = 0; j < 8; ++j)
        w8[j] = f2b(__expf(b2f(r8[j]) - mrow) + GAMMA_C * __expf(b2f(f8[j]) - mrow));
      *(uint4*)&As[row][ssg << 3] = *(const uint4*)w8;
    }
    __syncthreads();
#pragma unroll
    for (int kk = 0; kk < 2; ++kk) {
      bf16x8 a[4], b[4];
      const int koff = (((kk << 2) + l4) << 3) ^ swz;
#pragma unroll
      for (int i = 0; i < 4; ++i) {
        a[i] = *(const bf16x8*)&As[wm + (i << 4) + l15][koff];
        b[i] = *(const bf16x8*)&Bs[wn + (i << 4) + l15][koff];
      }
#pragma unroll
      for (int i = 0; i < 4; ++i)
#pragma unroll
        for (int j = 0; j < 4; ++j)
          acc[i][j] = __builtin_amdgcn_mfma_f32_16x16x32_bf16(a[i], b[j], acc[i][j], 0, 0, 0);
    }
    __syncthreads();
  }
#pragma unroll
  for (int i = 0; i < 4; ++i) {
    const int rloc = m0 + wm + (i << 4) + l4 * 4;
#pragma unroll
    for (int r = 0; r < 4; ++r) {
      const float linv = 1.0f / lvec[row0 + rloc + r];
#pragma unroll
      for (int j = 0; j < 4; ++j) {
        const int gn = n0 + wn + (j << 4) + l15;
        Out[(size_t)(row0 + rloc + r) * 512 + gn] = f2b(acc[i][j][r] * linv);
      }
    }
  }
}

// -------------------- online row max + sum(exp) reduction -------------------
__global__ __launch_bounds__(256)
void row_ml(const u16* __restrict__ sr, const u16* __restrict__ sf,
            float* __restrict__ mOut, float* __restrict__ lOut, int row0) {
  const int row = blockIdx.x, tid = threadIdx.x;
  const u16* pr = sr + (size_t)row * 8192;
  const u16* pf = sf + (size_t)row * 8192;
  float mloc = -1e30f, lloc = 0.f;
  for (int c0 = tid * 8; c0 < 8192; c0 += 2048) {
    const uint4 rv = *(const uint4*)(pr + c0);
    const uint4 fv = *(const uint4*)(pf + c0);
    const u16* r8 = (const u16*)&rv;
    const u16* f8 = (const u16*)&fv;
    float vr[8], vf[8], cmax = -1e30f;
#pragma unroll
    for (int j = 0; j < 8; ++j) {
      vr[j] = b2f(r8[j]); vf[j] = b2f(f8[j]);
      cmax = fmaxf(cmax, fmaxf(vr[j], vf[j]));
    }
    if (cmax > mloc) { lloc *= __expf(mloc - cmax); mloc = cmax; }
#pragma unroll
    for (int j = 0; j < 8; ++j)
      lloc += __expf(vr[j] - mloc) + GAMMA_C * __expf(vf[j] - mloc);
  }
  __shared__ float ms[256], ls[256];
  ms[tid] = mloc; ls[tid] = lloc;
  __syncthreads();
  for (int s = 128; s > 0; s >>= 1) {
    if (tid < s) {
      const float m1 = ms[tid], l1 = ls[tid];
      const float m2 = ms[tid + s], l2 = ls[tid + s];
      const float nm = fmaxf(m1, m2);
      ms[tid] = nm;
      ls[tid] = l1 * __expf(m1 - nm) + l2 * __expf(m2 - nm);
    }
    __syncthreads();
  }
  if (tid == 0) { mOut[row0 + row] = ms[0]; lOut[row0 + row] = ls[0]; }
}

// ------------------------------ residual + LN -------------------------------
__global__ __launch_bounds__(256)
void ln_fused(const u16* __restrict__ a, const u16* __restrict__ b,
              const void* __restrict__ g, const void* __restrict__ be,
              u16* __restrict__ out, const int* __restrict__ flags) {
  const int row = blockIdx.x, tid = threadIdx.x;
  const int f32m = flags[2];
  const size_t off = (size_t)row * 512 + tid * 2;
  const float v0 = b2f(a[off]) + b2f(b[off]);
  const float v1 = b2f(a[off + 1]) + b2f(b[off + 1]);
  __shared__ float r1[256], r2[256];
  r1[tid] = v0 + v1;
  r2[tid] = v0 * v0 + v1 * v1;
  __syncthreads();
  for (int s = 128; s > 0; s >>= 1) {
    if (tid < s) { r1[tid] += r1[tid + s]; r2[tid] += r2[tid + s]; }
    __syncthreads();
  }
  const float mu = r1[0] * (1.f / 512.f);
  const float var = r2[0] * (1.f / 512.f) - mu * mu;
  const float rs = rsqrtf(var + 1e-5f);
  out[off]     = f2b((v0 - mu) * rs * fl_at(g, tid * 2, f32m)     + fl_at(be, tid * 2, f32m));
  out[off + 1] = f2b((v1 - mu) * rs * fl_at(g, tid * 2 + 1, f32m) + fl_at(be, tid * 2 + 1, f32m));
}

// ------------------------------- host driver --------------------------------
extern "C" void kernel_launch(void* const* d_in, const int* in_sizes, int n_in,
                              void* d_out, int out_size, void* d_ws, size_t ws_size,
                              hipStream_t stream) {
  const void* x = d_in[0];
  const void* dropidx = d_in[1];
  const void* rmask = d_in[2];
  const void* fmask = d_in[3];

  char* base = (char*)d_ws;
  size_t cur = 0;
  auto alloc = [&](size_t b) -> void* {
    void* p = base + cur;
    cur += (b + 255) & ~(size_t)255;
    return p;
  };

  int* flags = (int*)alloc(256);
  u16* Wt[11];
  for (int i = 0; i < 11; ++i) Wt[i] = (u16*)alloc((size_t)512 * 512 * 2);
  u16* wff1t = (u16*)alloc((size_t)2048 * 512 * 2);
  u16* wff2t = (u16*)alloc((size_t)512 * 2048 * 2);
  const size_t ND2 = (size_t)8192 * 512 * 2;
  u16* dropx = (u16*)alloc(ND2);
  u16* Qr = (u16*)alloc(ND2);
  u16* Kr = (u16*)alloc(ND2);
  u16* Qf = (u16*)alloc(ND2);
  u16* Kf = (u16*)alloc(ND2);
  u16* Vt = (u16*)alloc(ND2);           // V^T [512,8192], written by gemm act=2
  u16* AO = (u16*)alloc(ND2);
  u16* H1 = (u16*)alloc(ND2);
  u16* H2 = (u16*)alloc(ND2);
  u16* FF2 = (u16*)alloc(ND2);
  u16* FF1 = (u16*)alloc((size_t)2048 * 2048 * 2);   // FF row-chunked by 2048
  float* mvec = (float*)alloc((size_t)8192 * 4);
  float* lvec = (float*)alloc((size_t)8192 * 4);

  const size_t srfull = (size_t)8192 * 8192 * 2;
  int c = 1;
  while (c < 64 && cur + 2 * ((srfull / c + 255) & ~(size_t)255) > ws_size) c <<= 1;
  const int rows = 8192 / c;
  u16* sr = (u16*)alloc(srfull / c);
  u16* sf = (u16*)alloc(srfull / c);

  // Diagnostics (captured by pytest on failure).
  fprintf(stderr, "[kernel_launch] ws_size=%zu need=%zu chunks=%d n_in=%d out=%d sizes:",
          ws_size, cur, c, n_in, out_size);
  for (int i = 0; i < n_in && i < 26; ++i) fprintf(stderr, " %d", in_sizes[i]);
  fprintf(stderr, "%s\n", (cur > ws_size) ? "  *** WS OVERFLOW ***" : "");

  detect_all<<<1, 256, 0, stream>>>((const unsigned char*)rmask, x, dropidx, flags);

  const dim3 tb(32, 8);
  const void* Wsrc[11] = {
    d_in[4], d_in[5], d_in[6], d_in[7], d_in[8],
    d_in[9], d_in[10], d_in[11], d_in[12], d_in[13], d_in[24]
  };
  for (int i = 0; i < 11; ++i)
    transpose_cvt<<<dim3(16, 16), tb, 0, stream>>>(Wsrc[i], Wt[i], 512, 512, flags);
  transpose_cvt<<<dim3(64, 16), tb, 0, stream>>>(d_in[14], wff1t, 512, 2048, flags);
  transpose_cvt<<<dim3(16, 64), tb, 0, stream>>>(d_in[16], wff2t, 2048, 512, flags);

  cvt_to_bf16<<<(8192 * 512 + 255) / 256, 256, 0, stream>>>(x, dropx, 8192 * 512, flags);
  zero_drop<<<(NG + 255) / 256, 256, 0, stream>>>(dropx, dropidx, flags);

  auto gemm = [&](const u16* A, const u16* Bt, u16* Cc, int M, int Nn, int K,
                  const void* bias, int act, const void* mask, long long mrow0,
                  int trld) {
    gemm_bt<<<dim3(Nn / 128, M / 128), 256, 0, stream>>>(
        A, Bt, Cc, M, Nn, K, bias, act, mask, flags, mrow0, trld);
  };

  auto attention = [&](const u16* Hin, const u16* Wqr, const u16* Wkr,
                       const u16* Wqf, const u16* Wkf, const u16* Wv, u16* Oout) {
    gemm(Hin, Wqr, Qr, 8192, 512, 512, nullptr, 0, nullptr, 0, 0);
    gemm(Hin, Wkr, Kr, 8192, 512, 512, nullptr, 0, nullptr, 0, 0);
    gemm(Hin, Wqf, Qf, 8192, 512, 512, nullptr, 0, nullptr, 0, 0);
    gemm(Hin, Wkf, Kf, 8192, 512, 512, nullptr, 0, nullptr, 0, 0);
    gemm(Hin, Wv,  Vt, 8192, 512, 512, nullptr, 2, nullptr, 0, 8192);
    for (int ch = 0; ch < c; ++ch) {
      const int row0 = ch * rows;
      gemm(Qr + (size_t)row0 * 512, Kr, sr, rows, 8192, 512, nullptr, 0, rmask, row0, 0);
      gemm(Qf + (size_t)row0 * 512, Kf, sf, rows, 8192, 512, nullptr, 0, fmask, row0, 0);
      row_ml<<<rows, 256, 0, stream>>>(sr, sf, mvec, lvec, row0);
      gemm_pv<<<dim3(4, rows / 128), 256, 0, stream>>>(sr, sf, Vt, Oout, mvec, lvec, row0);
    }
  };

  // encoder
  attention(dropx, Wt[0], Wt[1], Wt[2], Wt[3], Wt[4], AO);
  ln_fused<<<8192, 256, 0, stream>>>(AO, dropx, d_in[18], d_in[19], H1, flags);
  for (int r0 = 0; r0 < 8192; r0 += 2048) {
    gemm(H1 + (size_t)r0 * 512, wff1t, FF1, 2048, 2048, 512, d_in[15], 1, nullptr, 0, 0);
    gemm(FF1, wff2t, FF2 + (size_t)r0 * 512, 2048, 512, 2048, d_in[17], 0, nullptr, 0, 0);
  }
  ln_fused<<<8192, 256, 0, stream>>>(H1, FF2, d_in[20], d_in[21], H2, flags);
  // decoder
  attention(H2, Wt[5], Wt[6], Wt[7], Wt[8], Wt[9], AO);
  ln_fused<<<8192, 256, 0, stream>>>(AO, H2, d_in[22], d_in[23], H1, flags);
  gemm(H1, Wt[10], FF2, 8192, 512, 512, d_in[25], 0, nullptr, 0, 0);
  gather_out_k<<<(NG + 255) / 256, 256, 0, stream>>>(x, FF2, dropidx, d_out, flags);
}

// Round 3
// 2434.774 us; speedup vs baseline: 1.3064x; 1.3064x over previous
//
#include <hip/hip_runtime.h>
#include <cstdint>
#include <cstddef>
#include <cstdio>

// ---------------------------------------------------------------------------
// SpaceFormerImputation on MI355X (gfx950) — round 3.
// Key round-3 changes vs round 2 (which passed at 3181 us):
//  * No row-max: w = exp(sr) + gamma*exp(sf) computed unnormalized (masked -> 0,
//    |s| <~ 10 so f32-safe; the max & 1/(1+gamma) cancel in normalization).
//    sr-kernel stores er=exp(sr); sf-kernel merges w in place into er buffer;
//    row sums via per-row atomics. row_ml kernel and mvec eliminated.
//  * PV is now a PURE bf16 GEMM with K=8192 (no expf in the hot loop); its
//    working set (w 134MB + Vt 8MB) fits the 256MB L3.
//  * All GEMM epilogues go through a 32KB LDS round-trip (XOR-swizzled) so
//    global stores + mask loads are 16B-vectorized (was 128 scalar VMEM ops).
//  * One fused QKV projection GEMM (N=2560, V stored transposed in-epilogue);
//    FF un-chunked.
// Runtime dtype flags: [0] mask fmt 0=i32,1=u8,2=bf16,3=f32; [1] idx int64;
// [2] float world f32(1)/bf16(0).
// ---------------------------------------------------------------------------

typedef unsigned short u16;
typedef __bf16 bf16x8 __attribute__((ext_vector_type(8)));
typedef float f32x4 __attribute__((ext_vector_type(4)));

#define GAMMA_C 0.5f
#define SCALE_C 0.04419417382415922f   // 1/sqrt(512)
#define NG      (8192 * 102)

__device__ __forceinline__ float b2f(u16 u) {
  union { unsigned int i; float f; } c; c.i = ((unsigned int)u) << 16; return c.f;
}
__device__ __forceinline__ u16 f2b(float f) {
  union { float f; unsigned int i; } c; c.f = f;
  unsigned int u = c.i + 0x7FFFu + ((c.i >> 16) & 1u);
  return (u16)(u >> 16);
}
__device__ __forceinline__ float gelu_exact(float x) {
  return 0.5f * x * (1.0f + erff(x * 0.70710678118654752f));
}
__device__ __forceinline__ int idx_at(const void* p, int i, int i64) {
  return i64 ? (int)((const long long*)p)[i] : ((const int*)p)[i];
}
__device__ __forceinline__ float fl_at(const void* p, size_t i, int f32m) {
  return f32m ? ((const float*)p)[i] : b2f(((const u16*)p)[i]);
}
// 8 consecutive mask values starting at element index `base` (8-aligned).
__device__ __forceinline__ void mask8(const void* m, size_t base, int f, bool o[8]) {
  if (f == 1) {
    unsigned long long v = *(const unsigned long long*)((const unsigned char*)m + base);
#pragma unroll
    for (int e = 0; e < 8; ++e) o[e] = ((v >> (8 * e)) & 0xFF) != 0;
  } else if (f == 0) {
    const uint4 a = *(const uint4*)((const int*)m + base);
    const uint4 b = *(const uint4*)((const int*)m + base + 4);
    o[0] = a.x; o[1] = a.y; o[2] = a.z; o[3] = a.w;
    o[4] = b.x; o[5] = b.y; o[6] = b.z; o[7] = b.w;
  } else if (f == 2) {
    const uint4 v = *(const uint4*)((const u16*)m + base);
    const u16* p = (const u16*)&v;
#pragma unroll
    for (int e = 0; e < 8; ++e) o[e] = p[e] != 0;
  } else {
    const uint4 a = *(const uint4*)((const float*)m + base);
    const uint4 b = *(const uint4*)((const float*)m + base + 4);
    o[0] = a.x; o[1] = a.y; o[2] = a.z; o[3] = a.w;
    o[4] = b.x; o[5] = b.y; o[6] = b.z; o[7] = b.w;
  }
}

#define GLD16(g, l) __builtin_amdgcn_global_load_lds(                         \
    (const __attribute__((address_space(1))) void*)(g),                       \
    (__attribute__((address_space(3))) void*)(l), 16, 0, 0)

// ----------------------------- dtype sniffing ------------------------------
__global__ void detect_all(const unsigned char* __restrict__ rmask,
                           const void* __restrict__ xin,
                           const void* __restrict__ idx,
                           int* __restrict__ flags) {
  __shared__ int nz[4];
  __shared__ int mx, bl;
  const int t = threadIdx.x;
  if (t < 4) nz[t] = 0;
  if (t == 0) { mx = 0; bl = 0; }
  __syncthreads();
  int cnt = 0, lm = 0;
  for (int i = t; i < 4096; i += 256) {
    const int v = rmask[i];
    if (v) { ++cnt; if (v > lm) lm = v; }
  }
  if (cnt) atomicAdd(&nz[t & 3], cnt);
  if (lm) atomicMax(&mx, lm);
  int bcnt = 0;
  for (int i = t; i < 2048; i += 256) {
    const u16 u = ((const u16*)xin)[2 * i];
    const int e = (u >> 7) & 0xFF;
    if ((e >= 110 && e <= 141) || u == 0) ++bcnt;
  }
  atomicAdd(&bl, bcnt);
  __syncthreads();
  if (t == 0) {
    int f;
    if (nz[1] == 0 && nz[2] == 0 && nz[3] == 0) f = 0;
    else if (nz[0] == 0 && nz[1] == 0) f = 3;
    else if (mx <= 1) f = 1;
    else f = 2;
    flags[0] = f;
    flags[2] = (bl >= 1536) ? 0 : 1;
    int ok = 1, prev = -1;
    for (int j = 0; j < 102; ++j) {
      const int v = ((const int*)idx)[j];
      if (v <= prev || v < 0 || v >= 512) { ok = 0; break; }
      prev = v;
    }
    flags[1] = ok ? 0 : 1;
  }
}

// ---------------------- transpose + convert to bf16 ------------------------
__global__ void transpose_cvt(const void* __restrict__ in, u16* __restrict__ out,
                              int R, int C, const int* __restrict__ flags) {
  __shared__ u16 tile[32][33];
  const int f32m = flags[2];
  const int c0 = blockIdx.x * 32, r0 = blockIdx.y * 32;
  const int tx = threadIdx.x, ty = threadIdx.y;   // (32,8)
  for (int i = ty; i < 32; i += 8) {
    const size_t src = (size_t)(r0 + i) * C + (c0 + tx);
    tile[i][tx] = f32m ? f2b(((const float*)in)[src]) : ((const u16*)in)[src];
  }
  __syncthreads();
  for (int i = ty; i < 32; i += 8)
    out[(size_t)(c0 + i) * R + (r0 + tx)] = tile[tx][i];
}

// ------------------------------ small utils --------------------------------
__global__ void cvt_to_bf16(const void* __restrict__ in, u16* __restrict__ out,
                            int n, const int* __restrict__ flags) {
  const int i = blockIdx.x * blockDim.x + threadIdx.x;
  if (i < n)
    out[i] = flags[2] ? f2b(((const float*)in)[i]) : ((const u16*)in)[i];
}
__global__ void zero_f32(float* __restrict__ p, int n) {
  const int i = blockIdx.x * blockDim.x + threadIdx.x;
  if (i < n) p[i] = 0.f;
}
__global__ void zero_drop(u16* __restrict__ dx, const void* __restrict__ idx,
                          const int* __restrict__ flags) {
  const int i = blockIdx.x * blockDim.x + threadIdx.x;
  if (i < NG) {
    const int row = i / 102;
    dx[(size_t)row * 512 + idx_at(idx, i, flags[1])] = 0;
  }
}
__global__ void gather_out_k(const void* __restrict__ x, const u16* __restrict__ h,
                             const void* __restrict__ idx, void* __restrict__ out,
                             const int* __restrict__ flags) {
  const int i = blockIdx.x * blockDim.x + threadIdx.x;
  if (i < NG) {
    const int row = i / 102;
    const int c = idx_at(idx, i, flags[1]);
    const size_t src = (size_t)row * 512 + c;
    if (flags[2]) {
      ((float*)out)[i] = ((const float*)x)[src];
      ((float*)out)[NG + i] = b2f(h[src]);
    } else {
      ((u16*)out)[i] = ((const u16*)x)[src];
      ((u16*)out)[NG + i] = h[src];
    }
  }
}

// ------------------------------ GEMM (B^T) ---------------------------------
// C[M,Nn] = A[M,K] @ Bt[Nn,K]^T (bf16). 128x128 tile, BK=64, 2x2 waves of
// 64x64, 16x16x32 MFMA, XOR-swizzled LDS staging via global_load_lds(16B).
// Epilogue: acc -> (mode transform in C-frag layout) -> bf16 into 32KB LDS
// (chunk-XOR swizzle) -> barrier -> vectorized 16B global stores.
// modes: 0 plain(+bias)  1 gelu(+bias)  2 QKV split (n0<2048 -> C=P; else
// transposed store into aux=Vt)  3 score-r: er=mask?0:exp(s*scale)
// 4 score-f: w=aux_er + (mask?0:gamma*exp(s*scale)), in-place store + row-sum
// atomics into lvec  5 PV: scale rows by 1/lvec.
__global__ __launch_bounds__(256)
void gemm_bt(const u16* __restrict__ A, int lda,
             const u16* __restrict__ Bt, int ldb,
             u16* __restrict__ C, int ldc,
             int M, int Nn, int K, int mode,
             const void* __restrict__ bias,
             const void* __restrict__ mask, const int* __restrict__ flags,
             u16* __restrict__ aux, float* __restrict__ lvec) {
  __shared__ alignas(16) u16 smem[16384];       // As=smem[0:8192], Bs=+8192
  u16* As = smem;
  u16* Bs = smem + 8192;
  const int tid = threadIdx.x;
  const int lane = tid & 63, wave = tid >> 6;
  const int l15 = lane & 15, l4 = lane >> 4;
  const int wm = (wave >> 1) << 6, wn = (wave & 1) << 6;
  const int m0 = blockIdx.y << 7, n0 = blockIdx.x << 7;

  f32x4 acc[4][4];
#pragma unroll
  for (int i = 0; i < 4; ++i)
#pragma unroll
    for (int j = 0; j < 4; ++j) acc[i][j] = (f32x4){0.f, 0.f, 0.f, 0.f};

  const int lrow = lane >> 3;
  const int lcg = (lane & 7) ^ lrow;
  const u16* aG = A + (size_t)(m0 + wave * 8 + lrow) * lda + lcg * 8;
  const u16* bG = Bt + (size_t)(n0 + wave * 8 + lrow) * ldb + lcg * 8;
  u16* asDst = &As[(wave * 8) * 64];
  u16* bsDst = &Bs[(wave * 8) * 64];
  const int swz = (l15 & 7) << 3;

  for (int k0 = 0; k0 < K; k0 += 64) {
#pragma unroll
    for (int r = 0; r < 4; ++r) {
      GLD16(aG + (size_t)(r * 32) * lda + k0, asDst + r * 32 * 64);
      GLD16(bG + (size_t)(r * 32) * ldb + k0, bsDst + r * 32 * 64);
    }
    __syncthreads();
#pragma unroll
    for (int kk = 0; kk < 2; ++kk) {
      bf16x8 a[4], b[4];
      const int koff = (((kk << 2) + l4) << 3) ^ swz;
#pragma unroll
      for (int i = 0; i < 4; ++i) {
        a[i] = *(const bf16x8*)&As[(wm + (i << 4) + l15) * 64 + koff];
        b[i] = *(const bf16x8*)&Bs[(wn + (i << 4) + l15) * 64 + koff];
      }
#pragma unroll
      for (int i = 0; i < 4; ++i)
#pragma unroll
        for (int j = 0; j < 4; ++j)
          acc[i][j] = __builtin_amdgcn_mfma_f32_16x16x32_bf16(a[i], b[j], acc[i][j], 0, 0, 0);
    }
    __syncthreads();
  }

  const int f32m = flags[2];

  // mode 2, V-part: direct transposed store into Vt[512][8192]; skip phases.
  if (mode == 2 && n0 >= 2048) {
#pragma unroll
    for (int i = 0; i < 4; ++i) {
      const int rbase = m0 + wm + (i << 4) + l4 * 4;
#pragma unroll
      for (int j = 0; j < 4; ++j) {
        const int gn = n0 - 2048 + wn + (j << 4) + l15;
        ushort4 pk;
        pk.x = f2b(acc[i][j][0]); pk.y = f2b(acc[i][j][1]);
        pk.z = f2b(acc[i][j][2]); pk.w = f2b(acc[i][j][3]);
        *(ushort4*)&aux[(size_t)gn * 8192 + rbase] = pk;
      }
    }
    return;
  }

  // ---- phase 1: transform in C-frag layout, dump bf16 to swizzled LDS ----
#pragma unroll
  for (int i = 0; i < 4; ++i) {
    const int rl0 = wm + (i << 4) + l4 * 4;         // local row base (4 rows)
    float linv[4];
    if (mode == 5) {
#pragma unroll
      for (int r = 0; r < 4; ++r) linv[r] = 1.0f / lvec[m0 + rl0 + r];
    }
#pragma unroll
    for (int j = 0; j < 4; ++j) {
      const int cl = wn + (j << 4) + l15;           // local col
      float bv = 0.f;
      if (bias) bv = fl_at(bias, n0 + cl, f32m);
      const int chunk = cl >> 3, within = cl & 7;
#pragma unroll
      for (int r = 0; r < 4; ++r) {
        const int rl = rl0 + r;
        float v = acc[i][j][r];
        if (mode <= 2) { v += bv; if (mode == 1) v = gelu_exact(v); }
        else if (mode == 5) v *= linv[r];
        else v *= SCALE_C;                           // score modes
        const int wchunk = (chunk & 8) | ((chunk ^ rl) & 7);
        smem[rl * 128 + wchunk * 8 + within] = f2b(v);
      }
    }
  }
  __syncthreads();

  // ---- phase 2: row-linear, vectorized mask/er loads + 16B stores ----
  const int r = tid >> 1, h = tid & 1;
  const int grow = m0 + r;
  const int mf = (mask != nullptr) ? flags[0] : 0;
  float rowsum = 0.f;
#pragma unroll
  for (int cb = 0; cb < 8; ++cb) {
    const int chunkidx = h * 8 + cb;
    const int rchunk = (chunkidx & 8) | ((chunkidx ^ r) & 7);
    uint4 raw = *(const uint4*)&smem[r * 128 + rchunk * 8];
    const int gcol = n0 + chunkidx * 8;
    u16* v8 = (u16*)&raw;
    if (mode == 3 || mode == 4) {
      bool mk[8];
      mask8(mask, (size_t)grow * 8192 + gcol, mf, mk);
      u16 er8[8];
      if (mode == 4) *(uint4*)er8 = *(const uint4*)&aux[(size_t)grow * 8192 + gcol];
#pragma unroll
      for (int e = 0; e < 8; ++e) {
        float w = mk[e] ? 0.f : __expf(b2f(v8[e]));
        if (mode == 4) {
          w = GAMMA_C * w + b2f(er8[e]);
          rowsum += w;
        }
        v8[e] = f2b(w);
      }
    }
    *(uint4*)&C[(size_t)grow * ldc + gcol] = raw;
  }
  if (mode == 4) atomicAdd(&lvec[grow], rowsum);
}

// ------------------------------ residual + LN -------------------------------
__global__ __launch_bounds__(256)
void ln_fused(const u16* __restrict__ a, const u16* __restrict__ b,
              const void* __restrict__ g, const void* __restrict__ be,
              u16* __restrict__ out, const int* __restrict__ flags) {
  const int row = blockIdx.x, tid = threadIdx.x;
  const int f32m = flags[2];
  const size_t off = (size_t)row * 512 + tid * 2;
  const float v0 = b2f(a[off]) + b2f(b[off]);
  const float v1 = b2f(a[off + 1]) + b2f(b[off + 1]);
  __shared__ float r1[256], r2[256];
  r1[tid] = v0 + v1;
  r2[tid] = v0 * v0 + v1 * v1;
  __syncthreads();
  for (int s = 128; s > 0; s >>= 1) {
    if (tid < s) { r1[tid] += r1[tid + s]; r2[tid] += r2[tid + s]; }
    __syncthreads();
  }
  const float mu = r1[0] * (1.f / 512.f);
  const float var = r2[0] * (1.f / 512.f) - mu * mu;
  const float rs = rsqrtf(var + 1e-5f);
  out[off]     = f2b((v0 - mu) * rs * fl_at(g, tid * 2, f32m)     + fl_at(be, tid * 2, f32m));
  out[off + 1] = f2b((v1 - mu) * rs * fl_at(g, tid * 2 + 1, f32m) + fl_at(be, tid * 2 + 1, f32m));
}

// ------------------------------- host driver --------------------------------
extern "C" void kernel_launch(void* const* d_in, const int* in_sizes, int n_in,
                              void* d_out, int out_size, void* d_ws, size_t ws_size,
                              hipStream_t stream) {
  (void)in_sizes; (void)n_in; (void)out_size; (void)ws_size;
  const void* x = d_in[0];
  const void* dropidx = d_in[1];
  const void* rmask = d_in[2];
  const void* fmask = d_in[3];

  char* base = (char*)d_ws;
  size_t cur = 0;
  auto alloc = [&](size_t b) -> void* {
    void* p = base + cur;
    cur += (b + 255) & ~(size_t)255;
    return p;
  };

  int* flags = (int*)alloc(256);
  u16* Wqkv_enc = (u16*)alloc((size_t)2560 * 512 * 2);
  u16* Wqkv_dec = (u16*)alloc((size_t)2560 * 512 * 2);
  u16* wff1t = (u16*)alloc((size_t)2048 * 512 * 2);
  u16* wff2t = (u16*)alloc((size_t)512 * 2048 * 2);
  u16* headWt = (u16*)alloc((size_t)512 * 512 * 2);
  const size_t ND2 = (size_t)8192 * 512 * 2;
  u16* dropx = (u16*)alloc(ND2);
  u16* P = (u16*)alloc((size_t)8192 * 2048 * 2);   // [Qr|Kr|Qf|Kf] ld 2048
  u16* Vt = (u16*)alloc(ND2);                      // V^T [512][8192]
  u16* AO = (u16*)alloc(ND2);
  u16* H1 = (u16*)alloc(ND2);
  u16* H2 = (u16*)alloc(ND2);
  u16* FF2 = (u16*)alloc(ND2);
  u16* FF1 = (u16*)alloc((size_t)8192 * 2048 * 2);
  float* lvec = (float*)alloc((size_t)8192 * 4);
  u16* er = (u16*)alloc((size_t)8192 * 8192 * 2);  // er, then w in place

  detect_all<<<1, 256, 0, stream>>>((const unsigned char*)rmask, x, dropidx, flags);

  const dim3 tb(32, 8);
  // enc QKV weights: rows [Wq_r^T; Wk_r^T; Wq_f^T; Wk_f^T; Wv^T]
  for (int i = 0; i < 5; ++i)
    transpose_cvt<<<dim3(16, 16), tb, 0, stream>>>(d_in[4 + i],
        Wqkv_enc + (size_t)i * 512 * 512, 512, 512, flags);
  for (int i = 0; i < 5; ++i)
    transpose_cvt<<<dim3(16, 16), tb, 0, stream>>>(d_in[9 + i],
        Wqkv_dec + (size_t)i * 512 * 512, 512, 512, flags);
  transpose_cvt<<<dim3(64, 16), tb, 0, stream>>>(d_in[14], wff1t, 512, 2048, flags);
  transpose_cvt<<<dim3(16, 64), tb, 0, stream>>>(d_in[16], wff2t, 2048, 512, flags);
  transpose_cvt<<<dim3(16, 16), tb, 0, stream>>>(d_in[24], headWt, 512, 512, flags);

  cvt_to_bf16<<<(8192 * 512 + 255) / 256, 256, 0, stream>>>(x, dropx, 8192 * 512, flags);
  zero_drop<<<(NG + 255) / 256, 256, 0, stream>>>(dropx, dropidx, flags);

  auto gemm = [&](const u16* A, int lda, const u16* Bt, int ldb, u16* Cc, int ldc,
                  int M, int Nn, int K, int mode, const void* bias,
                  const void* mask, u16* aux) {
    gemm_bt<<<dim3(Nn / 128, M / 128), 256, 0, stream>>>(
        A, lda, Bt, ldb, Cc, ldc, M, Nn, K, mode, bias, mask, flags, aux, lvec);
  };

  auto attention = [&](const u16* Hin, const u16* Wqkv, u16* Oout) {
    zero_f32<<<32, 256, 0, stream>>>(lvec, 8192);
    gemm(Hin, 512, Wqkv, 512, P, 2048, 8192, 2560, 512, 2, nullptr, nullptr, Vt);
    gemm(P, 2048, P + 512, 2048, er, 8192, 8192, 8192, 512, 3, nullptr, rmask, nullptr);
    gemm(P + 1024, 2048, P + 1536, 2048, er, 8192, 8192, 8192, 512, 4, nullptr, fmask, er);
    gemm(er, 8192, Vt, 8192, Oout, 512, 8192, 512, 8192, 5, nullptr, nullptr, nullptr);
  };

  // encoder
  attention(dropx, Wqkv_enc, AO);
  ln_fused<<<8192, 256, 0, stream>>>(AO, dropx, d_in[18], d_in[19], H1, flags);
  gemm(H1, 512, wff1t, 512, FF1, 2048, 8192, 2048, 512, 1, d_in[15], nullptr, nullptr);
  gemm(FF1, 2048, wff2t, 2048, FF2, 512, 8192, 512, 2048, 0, d_in[17], nullptr, nullptr);
  ln_fused<<<8192, 256, 0, stream>>>(H1, FF2, d_in[20], d_in[21], H2, flags);
  // decoder
  attention(H2, Wqkv_dec, AO);
  ln_fused<<<8192, 256, 0, stream>>>(AO, H2, d_in[22], d_in[23], H1, flags);
  gemm(H1, 512, headWt, 512, FF2, 512, 8192, 512, 512, 0, d_in[25], nullptr, nullptr);
  gather_out_k<<<(NG + 255) / 256, 256, 0, stream>>>(x, FF2, dropidx, d_out, flags);
}

// Round 4
// 1812.296 us; speedup vs baseline: 1.7551x; 1.3435x over previous
//
#include <hip/hip_runtime.h>
#include <cstdint>
#include <cstddef>

// ---------------------------------------------------------------------------
// SpaceFormerImputation on MI355X (gfx950) — round 4.
// vs round 3 (2435 us): the 6 N^2 kernels were all latency-bound at ~2 TB/s,
// MfmaUtil 7%, 1.6 blocks/CU. Changes:
//  * score_fused: sr and sf computed in ONE kernel (two K-loops, one acc set,
//    sr parked in LDS between loops). er intermediate eliminated (-268 MB/attn,
//    -1 big dispatch/attn). 64KB LDS -> 2 blocks/CU, 16 waves/CU.
//  * masks packed to 8MB bitmasks once (masks are i32 per round-3 FETCH);
//    score epilogue reads 8B/half-row instead of 32B/chunk.
//  * PV split-K (4 chunks -> 1024 blocks = 4 blocks/CU) with f32 atomicAdd
//    into Oacc; divide/residual/LN fused into pv_ln.
// Runtime dtype flags: [0] mask fmt 0=i32,1=u8,2=bf16,3=f32; [1] idx int64;
// [2] float world f32(1)/bf16(0).
// ---------------------------------------------------------------------------

typedef unsigned short u16;
typedef __bf16 bf16x8 __attribute__((ext_vector_type(8)));
typedef float f32x4 __attribute__((ext_vector_type(4)));

#define GAMMA_C 0.5f
#define SCALE_C 0.04419417382415922f   // 1/sqrt(512)
#define NG      (8192 * 102)

__device__ __forceinline__ float b2f(u16 u) {
  union { unsigned int i; float f; } c; c.i = ((unsigned int)u) << 16; return c.f;
}
__device__ __forceinline__ u16 f2b(float f) {
  union { float f; unsigned int i; } c; c.f = f;
  unsigned int u = c.i + 0x7FFFu + ((c.i >> 16) & 1u);
  return (u16)(u >> 16);
}
__device__ __forceinline__ float gelu_exact(float x) {
  return 0.5f * x * (1.0f + erff(x * 0.70710678118654752f));
}
__device__ __forceinline__ int idx_at(const void* p, int i, int i64) {
  return i64 ? (int)((const long long*)p)[i] : ((const int*)p)[i];
}
__device__ __forceinline__ float fl_at(const void* p, size_t i, int f32m) {
  return f32m ? ((const float*)p)[i] : b2f(((const u16*)p)[i]);
}
__device__ __forceinline__ void mask8(const void* m, size_t base, int f, bool o[8]) {
  if (f == 1) {
    unsigned long long v = *(const unsigned long long*)((const unsigned char*)m + base);
#pragma unroll
    for (int e = 0; e < 8; ++e) o[e] = ((v >> (8 * e)) & 0xFF) != 0;
  } else if (f == 0) {
    const uint4 a = *(const uint4*)((const int*)m + base);
    const uint4 b = *(const uint4*)((const int*)m + base + 4);
    o[0] = a.x; o[1] = a.y; o[2] = a.z; o[3] = a.w;
    o[4] = b.x; o[5] = b.y; o[6] = b.z; o[7] = b.w;
  } else if (f == 2) {
    const uint4 v = *(const uint4*)((const u16*)m + base);
    const u16* p = (const u16*)&v;
#pragma unroll
    for (int e = 0; e < 8; ++e) o[e] = p[e] != 0;
  } else {
    const uint4 a = *(const uint4*)((const float*)m + base);
    const uint4 b = *(const uint4*)((const float*)m + base + 4);
    o[0] = a.x; o[1] = a.y; o[2] = a.z; o[3] = a.w;
    o[4] = b.x; o[5] = b.y; o[6] = b.z; o[7] = b.w;
  }
}

#define GLD16(g, l) __builtin_amdgcn_global_load_lds(                         \
    (const __attribute__((address_space(1))) void*)(g),                       \
    (__attribute__((address_space(3))) void*)(l), 16, 0, 0)

// ----------------------------- dtype sniffing ------------------------------
__global__ void detect_all(const unsigned char* __restrict__ rmask,
                           const void* __restrict__ xin,
                           const void* __restrict__ idx,
                           int* __restrict__ flags) {
  __shared__ int nz[4];
  __shared__ int mx, bl;
  const int t = threadIdx.x;
  if (t < 4) nz[t] = 0;
  if (t == 0) { mx = 0; bl = 0; }
  __syncthreads();
  int cnt = 0, lm = 0;
  for (int i = t; i < 4096; i += 256) {
    const int v = rmask[i];
    if (v) { ++cnt; if (v > lm) lm = v; }
  }
  if (cnt) atomicAdd(&nz[t & 3], cnt);
  if (lm) atomicMax(&mx, lm);
  int bcnt = 0;
  for (int i = t; i < 2048; i += 256) {
    const u16 u = ((const u16*)xin)[2 * i];
    const int e = (u >> 7) & 0xFF;
    if ((e >= 110 && e <= 141) || u == 0) ++bcnt;
  }
  atomicAdd(&bl, bcnt);
  __syncthreads();
  if (t == 0) {
    int f;
    if (nz[1] == 0 && nz[2] == 0 && nz[3] == 0) f = 0;
    else if (nz[0] == 0 && nz[1] == 0) f = 3;
    else if (mx <= 1) f = 1;
    else f = 2;
    flags[0] = f;
    flags[2] = (bl >= 1536) ? 0 : 1;
    int ok = 1, prev = -1;
    for (int j = 0; j < 102; ++j) {
      const int v = ((const int*)idx)[j];
      if (v <= prev || v < 0 || v >= 512) { ok = 0; break; }
      prev = v;
    }
    flags[1] = ok ? 0 : 1;
  }
}

// ----------------------- bitmask pack (1 bit/element) ----------------------
__global__ void bitmask_prep(const void* __restrict__ m, unsigned char* __restrict__ bm,
                             const int* __restrict__ flags) {
  const int i = blockIdx.x * 256 + threadIdx.x;   // output byte index, 8192*1024 total
  bool mk[8];
  mask8(m, (size_t)i * 8, flags[0], mk);
  unsigned char b = 0;
#pragma unroll
  for (int e = 0; e < 8; ++e) b |= (unsigned char)mk[e] << e;
  bm[i] = b;
}

// ---------------------- transpose + convert to bf16 ------------------------
__global__ void transpose_cvt(const void* __restrict__ in, u16* __restrict__ out,
                              int R, int C, const int* __restrict__ flags) {
  __shared__ u16 tile[32][33];
  const int f32m = flags[2];
  const int c0 = blockIdx.x * 32, r0 = blockIdx.y * 32;
  const int tx = threadIdx.x, ty = threadIdx.y;   // (32,8)
  for (int i = ty; i < 32; i += 8) {
    const size_t src = (size_t)(r0 + i) * C + (c0 + tx);
    tile[i][tx] = f32m ? f2b(((const float*)in)[src]) : ((const u16*)in)[src];
  }
  __syncthreads();
  for (int i = ty; i < 32; i += 8)
    out[(size_t)(c0 + i) * R + (r0 + tx)] = tile[tx][i];
}

// ------------------------------ small utils --------------------------------
__global__ void cvt_to_bf16(const void* __restrict__ in, u16* __restrict__ out,
                            int n, const int* __restrict__ flags) {
  const int i = blockIdx.x * blockDim.x + threadIdx.x;
  if (i < n)
    out[i] = flags[2] ? f2b(((const float*)in)[i]) : ((const u16*)in)[i];
}
__global__ void zero_f32(float* __restrict__ p, int n) {
  const int i = blockIdx.x * blockDim.x + threadIdx.x;
  if (i < n) p[i] = 0.f;
}
__global__ void zero_drop(u16* __restrict__ dx, const void* __restrict__ idx,
                          const int* __restrict__ flags) {
  const int i = blockIdx.x * blockDim.x + threadIdx.x;
  if (i < NG) {
    const int row = i / 102;
    dx[(size_t)row * 512 + idx_at(idx, i, flags[1])] = 0;
  }
}
__global__ void gather_out_k(const void* __restrict__ x, const u16* __restrict__ h,
                             const void* __restrict__ idx, void* __restrict__ out,
                             const int* __restrict__ flags) {
  const int i = blockIdx.x * blockDim.x + threadIdx.x;
  if (i < NG) {
    const int row = i / 102;
    const int c = idx_at(idx, i, flags[1]);
    const size_t src = (size_t)row * 512 + c;
    if (flags[2]) {
      ((float*)out)[i] = ((const float*)x)[src];
      ((float*)out)[NG + i] = b2f(h[src]);
    } else {
      ((u16*)out)[i] = ((const u16*)x)[src];
      ((u16*)out)[NG + i] = h[src];
    }
  }
}

// ------------------------------ GEMM (B^T) ---------------------------------
// C[M,Nn] = A[M,K] @ Bt[Nn,K]^T (bf16). 128x128 tile, BK=64, 2x2 waves,
// 16x16x32 MFMA, XOR-swizzled LDS. modes: 0 plain(+bias), 1 gelu(+bias),
// 2 QKV split (n0<2048 -> C; n0>=2048 -> transposed into aux=Vt).
__global__ __launch_bounds__(256)
void gemm_bt(const u16* __restrict__ A, int lda,
             const u16* __restrict__ Bt, int ldb,
             u16* __restrict__ C, int ldc,
             int K, int mode, const void* __restrict__ bias,
             const int* __restrict__ flags, u16* __restrict__ aux) {
  __shared__ alignas(16) u16 smem[16384];
  u16* As = smem;
  u16* Bs = smem + 8192;
  const int tid = threadIdx.x;
  const int lane = tid & 63, wave = tid >> 6;
  const int l15 = lane & 15, l4 = lane >> 4;
  const int wm = (wave >> 1) << 6, wn = (wave & 1) << 6;
  const int m0 = blockIdx.y << 7, n0 = blockIdx.x << 7;

  f32x4 acc[4][4];
#pragma unroll
  for (int i = 0; i < 4; ++i)
#pragma unroll
    for (int j = 0; j < 4; ++j) acc[i][j] = (f32x4){0.f, 0.f, 0.f, 0.f};

  const int lrow = lane >> 3;
  const int lcg = (lane & 7) ^ lrow;
  const u16* aG = A + (size_t)(m0 + wave * 8 + lrow) * lda + lcg * 8;
  const u16* bG = Bt + (size_t)(n0 + wave * 8 + lrow) * ldb + lcg * 8;
  u16* asDst = &As[(wave * 8) * 64];
  u16* bsDst = &Bs[(wave * 8) * 64];
  const int swz = (l15 & 7) << 3;

  for (int k0 = 0; k0 < K; k0 += 64) {
#pragma unroll
    for (int r = 0; r < 4; ++r) {
      GLD16(aG + (size_t)(r * 32) * lda + k0, asDst + r * 32 * 64);
      GLD16(bG + (size_t)(r * 32) * ldb + k0, bsDst + r * 32 * 64);
    }
    __syncthreads();
#pragma unroll
    for (int kk = 0; kk < 2; ++kk) {
      bf16x8 a[4], b[4];
      const int koff = (((kk << 2) + l4) << 3) ^ swz;
#pragma unroll
      for (int i = 0; i < 4; ++i) {
        a[i] = *(const bf16x8*)&As[(wm + (i << 4) + l15) * 64 + koff];
        b[i] = *(const bf16x8*)&Bs[(wn + (i << 4) + l15) * 64 + koff];
      }
#pragma unroll
      for (int i = 0; i < 4; ++i)
#pragma unroll
        for (int j = 0; j < 4; ++j)
          acc[i][j] = __builtin_amdgcn_mfma_f32_16x16x32_bf16(a[i], b[j], acc[i][j], 0, 0, 0);
    }
    __syncthreads();
  }

  const int f32m = flags[2];

  if (mode == 2 && n0 >= 2048) {        // V part -> transposed store into Vt
#pragma unroll
    for (int i = 0; i < 4; ++i) {
      const int rbase = m0 + wm + (i << 4) + l4 * 4;
#pragma unroll
      for (int j = 0; j < 4; ++j) {
        const int gn = n0 - 2048 + wn + (j << 4) + l15;
        ushort4 pk;
        pk.x = f2b(acc[i][j][0]); pk.y = f2b(acc[i][j][1]);
        pk.z = f2b(acc[i][j][2]); pk.w = f2b(acc[i][j][3]);
        *(ushort4*)&aux[(size_t)gn * 8192 + rbase] = pk;
      }
    }
    return;
  }

  // phase 1: transform in C-frag layout, bf16 into swizzled LDS
#pragma unroll
  for (int i = 0; i < 4; ++i) {
    const int rl0 = wm + (i << 4) + l4 * 4;
#pragma unroll
    for (int j = 0; j < 4; ++j) {
      const int cl = wn + (j << 4) + l15;
      float bv = 0.f;
      if (bias) bv = fl_at(bias, n0 + cl, f32m);
      const int chunk = cl >> 3, within = cl & 7;
#pragma unroll
      for (int r = 0; r < 4; ++r) {
        const int rl = rl0 + r;
        float v = acc[i][j][r] + bv;
        if (mode == 1) v = gelu_exact(v);
        const int wchunk = (chunk & 8) | ((chunk ^ rl) & 7);
        smem[rl * 128 + wchunk * 8 + within] = f2b(v);
      }
    }
  }
  __syncthreads();

  // phase 2: vectorized stores
  const int r = tid >> 1, h = tid & 1;
  const int grow = m0 + r;
#pragma unroll
  for (int cb = 0; cb < 8; ++cb) {
    const int chunkidx = h * 8 + cb;
    const int rchunk = (chunkidx & 8) | ((chunkidx ^ r) & 7);
    uint4 raw = *(const uint4*)&smem[r * 128 + rchunk * 8];
    *(uint4*)&C[(size_t)grow * ldc + n0 + chunkidx * 8] = raw;
  }
}

// --------------------------- fused dual score ------------------------------
// W[m,n] = maskr?0:exp(sr*scale) + gamma*(maskf?0:exp(sf*scale)) + row-sum
// atomics. Two sequential K=512 loops (Qr.Kr^T then Qf.Kf^T) sharing one acc
// set; raw sr*scale parked in srbuf (LDS) between loops; sf*scale parked in
// the (then-free) staging LDS. exp/mask/store/rowsum in phase 2.
__global__ __launch_bounds__(256)
void score_fused(const u16* __restrict__ P,          // [8192][2048] Qr|Kr|Qf|Kf
                 const unsigned char* __restrict__ bmr,
                 const unsigned char* __restrict__ bmf,
                 u16* __restrict__ W, float* __restrict__ lvec) {
  __shared__ alignas(16) u16 stage[16384];   // 32KB: staging, then sf tile
  __shared__ alignas(16) u16 srbuf[16384];   // 32KB: sr tile
  const int tid = threadIdx.x;
  const int lane = tid & 63, wave = tid >> 6;
  const int l15 = lane & 15, l4 = lane >> 4;
  const int wm = (wave >> 1) << 6, wn = (wave & 1) << 6;
  const int m0 = blockIdx.y << 7, n0 = blockIdx.x << 7;

  const int lrow = lane >> 3;
  const int lcg = (lane & 7) ^ lrow;
  const int swz = (l15 & 7) << 3;
  u16* asDst = &stage[(wave * 8) * 64];
  u16* bsDst = &stage[8192 + (wave * 8) * 64];

#pragma unroll
  for (int p = 0; p < 2; ++p) {
    f32x4 acc[4][4];
#pragma unroll
    for (int i = 0; i < 4; ++i)
#pragma unroll
      for (int j = 0; j < 4; ++j) acc[i][j] = (f32x4){0.f, 0.f, 0.f, 0.f};

    const u16* aG = P + (p ? 1024 : 0) + (size_t)(m0 + wave * 8 + lrow) * 2048 + lcg * 8;
    const u16* bG = P + (p ? 1536 : 512) + (size_t)(n0 + wave * 8 + lrow) * 2048 + lcg * 8;

    for (int k0 = 0; k0 < 512; k0 += 64) {
#pragma unroll
      for (int r = 0; r < 4; ++r) {
        GLD16(aG + (size_t)(r * 32) * 2048 + k0, asDst + r * 32 * 64);
        GLD16(bG + (size_t)(r * 32) * 2048 + k0, bsDst + r * 32 * 64);
      }
      __syncthreads();
#pragma unroll
      for (int kk = 0; kk < 2; ++kk) {
        bf16x8 a[4], b[4];
        const int koff = (((kk << 2) + l4) << 3) ^ swz;
#pragma unroll
        for (int i = 0; i < 4; ++i) {
          a[i] = *(const bf16x8*)&stage[(wm + (i << 4) + l15) * 64 + koff];
          b[i] = *(const bf16x8*)&stage[8192 + (wn + (i << 4) + l15) * 64 + koff];
        }
#pragma unroll
        for (int i = 0; i < 4; ++i)
#pragma unroll
          for (int j = 0; j < 4; ++j)
            acc[i][j] = __builtin_amdgcn_mfma_f32_16x16x32_bf16(a[i], b[j], acc[i][j], 0, 0, 0);
      }
      __syncthreads();
    }

    // dump s*scale tile (bf16, swizzled). p0 -> srbuf; p1 -> stage (now free).
    u16* buf = p ? stage : srbuf;
#pragma unroll
    for (int i = 0; i < 4; ++i) {
      const int rl0 = wm + (i << 4) + l4 * 4;
#pragma unroll
      for (int j = 0; j < 4; ++j) {
        const int cl = wn + (j << 4) + l15;
        const int chunk = cl >> 3, within = cl & 7;
#pragma unroll
        for (int r = 0; r < 4; ++r) {
          const int rl = rl0 + r;
          const int wchunk = (chunk & 8) | ((chunk ^ rl) & 7);
          buf[rl * 128 + wchunk * 8 + within] = f2b(acc[i][j][r] * SCALE_C);
        }
      }
    }
  }
  __syncthreads();

  // phase 2: w = exp(sr)*!mr + gamma*exp(sf)*!mf ; store + rowsum atomics
  const int r = tid >> 1, h = tid & 1;
  const int grow = m0 + r;
  const unsigned long long rm8 =
      *(const unsigned long long*)&bmr[(size_t)grow * 1024 + (n0 >> 3) + h * 8];
  const unsigned long long fm8 =
      *(const unsigned long long*)&bmf[(size_t)grow * 1024 + (n0 >> 3) + h * 8];
  float rowsum = 0.f;
#pragma unroll
  for (int cb = 0; cb < 8; ++cb) {
    const int chunkidx = h * 8 + cb;
    const int rchunk = (chunkidx & 8) | ((chunkidx ^ r) & 7);
    uint4 srv = *(const uint4*)&srbuf[r * 128 + rchunk * 8];
    const uint4 sfv = *(const uint4*)&stage[r * 128 + rchunk * 8];
    const u16* s8 = (const u16*)&srv;
    const u16* f8 = (const u16*)&sfv;
    const int rb = (int)(rm8 >> (8 * cb)) & 0xFF;
    const int fb = (int)(fm8 >> (8 * cb)) & 0xFF;
    u16* v8 = (u16*)&srv;
#pragma unroll
    for (int e = 0; e < 8; ++e) {
      const float wr = ((rb >> e) & 1) ? 0.f : __expf(b2f(s8[e]));
      const float wf = ((fb >> e) & 1) ? 0.f : __expf(b2f(f8[e]));
      const float w = wr + GAMMA_C * wf;
      rowsum += w;
      v8[e] = f2b(w);
    }
    *(uint4*)&W[(size_t)grow * 8192 + n0 + chunkidx * 8] = srv;
  }
  atomicAdd(&lvec[grow], rowsum);
}

// ------------------------------ PV split-K ---------------------------------
// Oacc[8192][512] (f32) += W[128-tile] @ V; K split in 4 chunks of 2048.
__global__ __launch_bounds__(256)
void gemm_pv_splitk(const u16* __restrict__ W, const u16* __restrict__ Vt,
                    float* __restrict__ Oacc) {
  __shared__ alignas(16) u16 smem[16384];
  u16* As = smem;
  u16* Bs = smem + 8192;
  const int tid = threadIdx.x;
  const int lane = tid & 63, wave = tid >> 6;
  const int l15 = lane & 15, l4 = lane >> 4;
  const int wm = (wave >> 1) << 6, wn = (wave & 1) << 6;
  const int m0 = blockIdx.y << 7, n0 = blockIdx.x << 7;
  const int kbase = blockIdx.z << 11;            // 4 chunks x 2048

  f32x4 acc[4][4];
#pragma unroll
  for (int i = 0; i < 4; ++i)
#pragma unroll
    for (int j = 0; j < 4; ++j) acc[i][j] = (f32x4){0.f, 0.f, 0.f, 0.f};

  const int lrow = lane >> 3;
  const int lcg = (lane & 7) ^ lrow;
  const u16* aG = W + (size_t)(m0 + wave * 8 + lrow) * 8192 + lcg * 8 + kbase;
  const u16* bG = Vt + (size_t)(n0 + wave * 8 + lrow) * 8192 + lcg * 8 + kbase;
  u16* asDst = &As[(wave * 8) * 64];
  u16* bsDst = &Bs[(wave * 8) * 64];
  const int swz = (l15 & 7) << 3;

  for (int k0 = 0; k0 < 2048; k0 += 64) {
#pragma unroll
    for (int r = 0; r < 4; ++r) {
      GLD16(aG + (size_t)(r * 32) * 8192 + k0, asDst + r * 32 * 64);
      GLD16(bG + (size_t)(r * 32) * 8192 + k0, bsDst + r * 32 * 64);
    }
    __syncthreads();
#pragma unroll
    for (int kk = 0; kk < 2; ++kk) {
      bf16x8 a[4], b[4];
      const int koff = (((kk << 2) + l4) << 3) ^ swz;
#pragma unroll
      for (int i = 0; i < 4; ++i) {
        a[i] = *(const bf16x8*)&As[(wm + (i << 4) + l15) * 64 + koff];
        b[i] = *(const bf16x8*)&Bs[(wn + (i << 4) + l15) * 64 + koff];
      }
#pragma unroll
      for (int i = 0; i < 4; ++i)
#pragma unroll
        for (int j = 0; j < 4; ++j)
          acc[i][j] = __builtin_amdgcn_mfma_f32_16x16x32_bf16(a[i], b[j], acc[i][j], 0, 0, 0);
    }
    __syncthreads();
  }

#pragma unroll
  for (int i = 0; i < 4; ++i) {
    const int rbase = m0 + wm + (i << 4) + l4 * 4;
#pragma unroll
    for (int j = 0; j < 4; ++j) {
      const int gn = n0 + wn + (j << 4) + l15;
#pragma unroll
      for (int r = 0; r < 4; ++r)
        atomicAdd(&Oacc[(size_t)(rbase + r) * 512 + gn], acc[i][j][r]);
    }
  }
}

// -------- fused: h = Oacc/lvec + residual; out = LN(h) (bf16) --------------
__global__ __launch_bounds__(256)
void pv_ln(const float* __restrict__ Oacc, const float* __restrict__ lvec,
           const u16* __restrict__ res, const void* __restrict__ g,
           const void* __restrict__ be, u16* __restrict__ out,
           const int* __restrict__ flags) {
  const int row = blockIdx.x, tid = threadIdx.x;
  const int f32m = flags[2];
  const size_t off = (size_t)row * 512 + tid * 2;
  const float linv = 1.0f / lvec[row];
  const float v0 = Oacc[off] * linv + b2f(res[off]);
  const float v1 = Oacc[off + 1] * linv + b2f(res[off + 1]);
  __shared__ float r1[256], r2[256];
  r1[tid] = v0 + v1;
  r2[tid] = v0 * v0 + v1 * v1;
  __syncthreads();
  for (int s = 128; s > 0; s >>= 1) {
    if (tid < s) { r1[tid] += r1[tid + s]; r2[tid] += r2[tid + s]; }
    __syncthreads();
  }
  const float mu = r1[0] * (1.f / 512.f);
  const float var = r2[0] * (1.f / 512.f) - mu * mu;
  const float rs = rsqrtf(var + 1e-5f);
  out[off]     = f2b((v0 - mu) * rs * fl_at(g, tid * 2, f32m)     + fl_at(be, tid * 2, f32m));
  out[off + 1] = f2b((v1 - mu) * rs * fl_at(g, tid * 2 + 1, f32m) + fl_at(be, tid * 2 + 1, f32m));
}

// ------------------------------ residual + LN -------------------------------
__global__ __launch_bounds__(256)
void ln_fused(const u16* __restrict__ a, const u16* __restrict__ b,
              const void* __restrict__ g, const void* __restrict__ be,
              u16* __restrict__ out, const int* __restrict__ flags) {
  const int row = blockIdx.x, tid = threadIdx.x;
  const int f32m = flags[2];
  const size_t off = (size_t)row * 512 + tid * 2;
  const float v0 = b2f(a[off]) + b2f(b[off]);
  const float v1 = b2f(a[off + 1]) + b2f(b[off + 1]);
  __shared__ float r1[256], r2[256];
  r1[tid] = v0 + v1;
  r2[tid] = v0 * v0 + v1 * v1;
  __syncthreads();
  for (int s = 128; s > 0; s >>= 1) {
    if (tid < s) { r1[tid] += r1[tid + s]; r2[tid] += r2[tid + s]; }
    __syncthreads();
  }
  const float mu = r1[0] * (1.f / 512.f);
  const float var = r2[0] * (1.f / 512.f) - mu * mu;
  const float rs = rsqrtf(var + 1e-5f);
  out[off]     = f2b((v0 - mu) * rs * fl_at(g, tid * 2, f32m)     + fl_at(be, tid * 2, f32m));
  out[off + 1] = f2b((v1 - mu) * rs * fl_at(g, tid * 2 + 1, f32m) + fl_at(be, tid * 2 + 1, f32m));
}

// ------------------------------- host driver --------------------------------
extern "C" void kernel_launch(void* const* d_in, const int* in_sizes, int n_in,
                              void* d_out, int out_size, void* d_ws, size_t ws_size,
                              hipStream_t stream) {
  (void)in_sizes; (void)n_in; (void)out_size; (void)ws_size;
  const void* x = d_in[0];
  const void* dropidx = d_in[1];
  const void* rmask = d_in[2];
  const void* fmask = d_in[3];

  char* base = (char*)d_ws;
  size_t cur = 0;
  auto alloc = [&](size_t b) -> void* {
    void* p = base + cur;
    cur += (b + 255) & ~(size_t)255;
    return p;
  };

  int* flags = (int*)alloc(256);
  u16* Wqkv_enc = (u16*)alloc((size_t)2560 * 512 * 2);
  u16* Wqkv_dec = (u16*)alloc((size_t)2560 * 512 * 2);
  u16* wff1t = (u16*)alloc((size_t)2048 * 512 * 2);
  u16* wff2t = (u16*)alloc((size_t)512 * 2048 * 2);
  u16* headWt = (u16*)alloc((size_t)512 * 512 * 2);
  const size_t ND2 = (size_t)8192 * 512 * 2;
  u16* dropx = (u16*)alloc(ND2);
  u16* P = (u16*)alloc((size_t)8192 * 2048 * 2);     // Qr|Kr|Qf|Kf, ld 2048
  u16* Vt = (u16*)alloc(ND2);                        // V^T [512][8192]
  u16* H1 = (u16*)alloc(ND2);
  u16* H2 = (u16*)alloc(ND2);
  u16* FF2 = (u16*)alloc(ND2);
  u16* FF1 = (u16*)alloc((size_t)8192 * 2048 * 2);
  unsigned char* bmr = (unsigned char*)alloc((size_t)8192 * 1024);
  unsigned char* bmf = (unsigned char*)alloc((size_t)8192 * 1024);
  float* lvec = (float*)alloc((size_t)8192 * 4);
  float* Oacc = (float*)alloc((size_t)8192 * 512 * 4);
  u16* Wb = (u16*)alloc((size_t)8192 * 8192 * 2);    // score weights w

  detect_all<<<1, 256, 0, stream>>>((const unsigned char*)rmask, x, dropidx, flags);
  bitmask_prep<<<32768, 256, 0, stream>>>(rmask, bmr, flags);
  bitmask_prep<<<32768, 256, 0, stream>>>(fmask, bmf, flags);

  const dim3 tb(32, 8);
  for (int i = 0; i < 5; ++i)
    transpose_cvt<<<dim3(16, 16), tb, 0, stream>>>(d_in[4 + i],
        Wqkv_enc + (size_t)i * 512 * 512, 512, 512, flags);
  for (int i = 0; i < 5; ++i)
    transpose_cvt<<<dim3(16, 16), tb, 0, stream>>>(d_in[9 + i],
        Wqkv_dec + (size_t)i * 512 * 512, 512, 512, flags);
  transpose_cvt<<<dim3(64, 16), tb, 0, stream>>>(d_in[14], wff1t, 512, 2048, flags);
  transpose_cvt<<<dim3(16, 64), tb, 0, stream>>>(d_in[16], wff2t, 2048, 512, flags);
  transpose_cvt<<<dim3(16, 16), tb, 0, stream>>>(d_in[24], headWt, 512, 512, flags);

  cvt_to_bf16<<<(8192 * 512 + 255) / 256, 256, 0, stream>>>(x, dropx, 8192 * 512, flags);
  zero_drop<<<(NG + 255) / 256, 256, 0, stream>>>(dropx, dropidx, flags);

  auto gemm = [&](const u16* A, int lda, const u16* Bt, int ldb, u16* Cc, int ldc,
                  int M, int Nn, int K, int mode, const void* bias, u16* aux) {
    gemm_bt<<<dim3(Nn / 128, M / 128), 256, 0, stream>>>(
        A, lda, Bt, ldb, Cc, ldc, K, mode, bias, flags, aux);
  };

  // attention: Hin -> pv_ln(out = LN(attn+res)) where res==Hin
  auto attention = [&](const u16* Hin, const u16* Wqkv, const void* lnG,
                       const void* lnB, u16* outLN) {
    zero_f32<<<32, 256, 0, stream>>>(lvec, 8192);
    zero_f32<<<16384, 256, 0, stream>>>(Oacc, 8192 * 512);
    gemm(Hin, 512, Wqkv, 512, P, 2048, 8192, 2560, 512, 2, nullptr, Vt);
    score_fused<<<dim3(64, 64), 256, 0, stream>>>(P, bmr, bmf, Wb, lvec);
    gemm_pv_splitk<<<dim3(4, 64, 4), 256, 0, stream>>>(Wb, Vt, Oacc);
    pv_ln<<<8192, 256, 0, stream>>>(Oacc, lvec, Hin, lnG, lnB, outLN, flags);
  };

  // encoder
  attention(dropx, Wqkv_enc, d_in[18], d_in[19], H1);
  gemm(H1, 512, wff1t, 512, FF1, 2048, 8192, 2048, 512, 1, d_in[15], nullptr);
  gemm(FF1, 2048, wff2t, 2048, FF2, 512, 8192, 512, 2048, 0, d_in[17], nullptr);
  ln_fused<<<8192, 256, 0, stream>>>(H1, FF2, d_in[20], d_in[21], H2, flags);
  // decoder
  attention(H2, Wqkv_dec, d_in[22], d_in[23], H1);
  gemm(H1, 512, headWt, 512, FF2, 512, 8192, 512, 512, 0, d_in[25], nullptr);
  gather_out_k<<<(NG + 255) / 256, 256, 0, stream>>>(x, FF2, dropidx, d_out, flags);
}

// Round 5
// 1546.556 us; speedup vs baseline: 2.0567x; 1.1718x over previous
//
#include <hip/hip_runtime.h>
#include <cstdint>
#include <cstddef>

// ---------------------------------------------------------------------------
// SpaceFormerImputation on MI355X (gfx950) — round 5.
// vs round 4 (1812 us): score_fused was occupancy-capped (64KB LDS -> 2
// blocks/CU, MfmaUtil 17%). Changes:
//  * score_fused v2: sr parked in 32 packed-bf16 VGPRs (srbuf LDS removed);
//    mask bit-tiles (4KB) pre-staged to LDS; exp/mask/rowsum done in C-frag
//    layout (broadcast ds_read_b64 + shfl_xor row reduce); LDS 64->36KB,
//    __launch_bounds__(256,3) -> 12 waves/CU.
//  * PV split-K writes 4 plain f32 slabs (no global atomics, no Oacc zeroing);
//    pv_ln sums slabs. Deterministic.
//  * 11 512x512 weight transposes batched into one launch.
// Runtime dtype flags: [0] mask fmt 0=i32,1=u8,2=bf16,3=f32; [1] idx int64;
// [2] float world f32(1)/bf16(0).
// ---------------------------------------------------------------------------

typedef unsigned short u16;
typedef __bf16 bf16x8 __attribute__((ext_vector_type(8)));
typedef float f32x4 __attribute__((ext_vector_type(4)));

#define GAMMA_C 0.5f
#define SCALE_C 0.04419417382415922f   // 1/sqrt(512)
#define NG      (8192 * 102)

__device__ __forceinline__ float b2f(u16 u) {
  union { unsigned int i; float f; } c; c.i = ((unsigned int)u) << 16; return c.f;
}
__device__ __forceinline__ u16 f2b(float f) {
  union { float f; unsigned int i; } c; c.f = f;
  unsigned int u = c.i + 0x7FFFu + ((c.i >> 16) & 1u);
  return (u16)(u >> 16);
}
__device__ __forceinline__ float gelu_exact(float x) {
  return 0.5f * x * (1.0f + erff(x * 0.70710678118654752f));
}
__device__ __forceinline__ int idx_at(const void* p, int i, int i64) {
  return i64 ? (int)((const long long*)p)[i] : ((const int*)p)[i];
}
__device__ __forceinline__ float fl_at(const void* p, size_t i, int f32m) {
  return f32m ? ((const float*)p)[i] : b2f(((const u16*)p)[i]);
}
__device__ __forceinline__ void mask8(const void* m, size_t base, int f, bool o[8]) {
  if (f == 1) {
    unsigned long long v = *(const unsigned long long*)((const unsigned char*)m + base);
#pragma unroll
    for (int e = 0; e < 8; ++e) o[e] = ((v >> (8 * e)) & 0xFF) != 0;
  } else if (f == 0) {
    const uint4 a = *(const uint4*)((const int*)m + base);
    const uint4 b = *(const uint4*)((const int*)m + base + 4);
    o[0] = a.x; o[1] = a.y; o[2] = a.z; o[3] = a.w;
    o[4] = b.x; o[5] = b.y; o[6] = b.z; o[7] = b.w;
  } else if (f == 2) {
    const uint4 v = *(const uint4*)((const u16*)m + base);
    const u16* p = (const u16*)&v;
#pragma unroll
    for (int e = 0; e < 8; ++e) o[e] = p[e] != 0;
  } else {
    const uint4 a = *(const uint4*)((const float*)m + base);
    const uint4 b = *(const uint4*)((const float*)m + base + 4);
    o[0] = a.x; o[1] = a.y; o[2] = a.z; o[3] = a.w;
    o[4] = b.x; o[5] = b.y; o[6] = b.z; o[7] = b.w;
  }
}

#define GLD16(g, l) __builtin_amdgcn_global_load_lds(                         \
    (const __attribute__((address_space(1))) void*)(g),                       \
    (__attribute__((address_space(3))) void*)(l), 16, 0, 0)

// ----------------------------- dtype sniffing ------------------------------
__global__ void detect_all(const unsigned char* __restrict__ rmask,
                           const void* __restrict__ xin,
                           const void* __restrict__ idx,
                           int* __restrict__ flags) {
  __shared__ int nz[4];
  __shared__ int mx, bl;
  const int t = threadIdx.x;
  if (t < 4) nz[t] = 0;
  if (t == 0) { mx = 0; bl = 0; }
  __syncthreads();
  int cnt = 0, lm = 0;
  for (int i = t; i < 4096; i += 256) {
    const int v = rmask[i];
    if (v) { ++cnt; if (v > lm) lm = v; }
  }
  if (cnt) atomicAdd(&nz[t & 3], cnt);
  if (lm) atomicMax(&mx, lm);
  int bcnt = 0;
  for (int i = t; i < 2048; i += 256) {
    const u16 u = ((const u16*)xin)[2 * i];
    const int e = (u >> 7) & 0xFF;
    if ((e >= 110 && e <= 141) || u == 0) ++bcnt;
  }
  atomicAdd(&bl, bcnt);
  __syncthreads();
  if (t == 0) {
    int f;
    if (nz[1] == 0 && nz[2] == 0 && nz[3] == 0) f = 0;
    else if (nz[0] == 0 && nz[1] == 0) f = 3;
    else if (mx <= 1) f = 1;
    else f = 2;
    flags[0] = f;
    flags[2] = (bl >= 1536) ? 0 : 1;
    int ok = 1, prev = -1;
    for (int j = 0; j < 102; ++j) {
      const int v = ((const int*)idx)[j];
      if (v <= prev || v < 0 || v >= 512) { ok = 0; break; }
      prev = v;
    }
    flags[1] = ok ? 0 : 1;
  }
}

// ----------------------- bitmask pack (1 bit/element) ----------------------
__global__ void bitmask_prep(const void* __restrict__ mr, const void* __restrict__ mf,
                             unsigned char* __restrict__ bmr, unsigned char* __restrict__ bmf,
                             const int* __restrict__ flags) {
  const int i = blockIdx.x * 256 + threadIdx.x;   // byte index, 8192*1024 total
  const int f = flags[0];
  bool mk[8];
  mask8(mr, (size_t)i * 8, f, mk);
  unsigned char b = 0;
#pragma unroll
  for (int e = 0; e < 8; ++e) b |= (unsigned char)mk[e] << e;
  bmr[i] = b;
  mask8(mf, (size_t)i * 8, f, mk);
  b = 0;
#pragma unroll
  for (int e = 0; e < 8; ++e) b |= (unsigned char)mk[e] << e;
  bmf[i] = b;
}

// ---------------------- transpose + convert to bf16 ------------------------
struct PtrPack { const void* p[11]; };
__global__ void transpose_cvt_b(PtrPack srcs, u16* __restrict__ out,
                                const int* __restrict__ flags) {
  // batched 512x512 transposes: z = matrix index
  __shared__ u16 tile[32][33];
  const void* in = srcs.p[blockIdx.z];
  u16* o = out + (size_t)blockIdx.z * 512 * 512;
  const int f32m = flags[2];
  const int c0 = blockIdx.x * 32, r0 = blockIdx.y * 32;
  const int tx = threadIdx.x, ty = threadIdx.y;   // (32,8)
  for (int i = ty; i < 32; i += 8) {
    const size_t src = (size_t)(r0 + i) * 512 + (c0 + tx);
    tile[i][tx] = f32m ? f2b(((const float*)in)[src]) : ((const u16*)in)[src];
  }
  __syncthreads();
  for (int i = ty; i < 32; i += 8)
    o[(size_t)(c0 + i) * 512 + (r0 + tx)] = tile[tx][i];
}
__global__ void transpose_cvt(const void* __restrict__ in, u16* __restrict__ out,
                              int R, int C, const int* __restrict__ flags) {
  __shared__ u16 tile[32][33];
  const int f32m = flags[2];
  const int c0 = blockIdx.x * 32, r0 = blockIdx.y * 32;
  const int tx = threadIdx.x, ty = threadIdx.y;
  for (int i = ty; i < 32; i += 8) {
    const size_t src = (size_t)(r0 + i) * C + (c0 + tx);
    tile[i][tx] = f32m ? f2b(((const float*)in)[src]) : ((const u16*)in)[src];
  }
  __syncthreads();
  for (int i = ty; i < 32; i += 8)
    out[(size_t)(c0 + i) * R + (r0 + tx)] = tile[tx][i];
}

// ------------------------------ small utils --------------------------------
__global__ void cvt_to_bf16(const void* __restrict__ in, u16* __restrict__ out,
                            int n, const int* __restrict__ flags) {
  const int i = blockIdx.x * blockDim.x + threadIdx.x;
  if (i < n)
    out[i] = flags[2] ? f2b(((const float*)in)[i]) : ((const u16*)in)[i];
}
__global__ void zero_f32(float* __restrict__ p, int n) {
  const int i = blockIdx.x * blockDim.x + threadIdx.x;
  if (i < n) p[i] = 0.f;
}
__global__ void zero_drop(u16* __restrict__ dx, const void* __restrict__ idx,
                          const int* __restrict__ flags) {
  const int i = blockIdx.x * blockDim.x + threadIdx.x;
  if (i < NG) {
    const int row = i / 102;
    dx[(size_t)row * 512 + idx_at(idx, i, flags[1])] = 0;
  }
}
__global__ void gather_out_k(const void* __restrict__ x, const u16* __restrict__ h,
                             const void* __restrict__ idx, void* __restrict__ out,
                             const int* __restrict__ flags) {
  const int i = blockIdx.x * blockDim.x + threadIdx.x;
  if (i < NG) {
    const int row = i / 102;
    const int c = idx_at(idx, i, flags[1]);
    const size_t src = (size_t)row * 512 + c;
    if (flags[2]) {
      ((float*)out)[i] = ((const float*)x)[src];
      ((float*)out)[NG + i] = b2f(h[src]);
    } else {
      ((u16*)out)[i] = ((const u16*)x)[src];
      ((u16*)out)[NG + i] = h[src];
    }
  }
}

// ------------------------------ GEMM (B^T) ---------------------------------
// C[M,Nn] = A[M,K] @ Bt[Nn,K]^T (bf16). 128x128 tile, BK=64, 2x2 waves,
// 16x16x32 MFMA, XOR-swizzled LDS. modes: 0 plain(+bias), 1 gelu(+bias),
// 2 QKV split (n0<2048 -> C; n0>=2048 -> transposed into aux=Vt).
__global__ __launch_bounds__(256)
void gemm_bt(const u16* __restrict__ A, int lda,
             const u16* __restrict__ Bt, int ldb,
             u16* __restrict__ C, int ldc,
             int K, int mode, const void* __restrict__ bias,
             const int* __restrict__ flags, u16* __restrict__ aux) {
  __shared__ alignas(16) u16 smem[16384];
  u16* As = smem;
  u16* Bs = smem + 8192;
  const int tid = threadIdx.x;
  const int lane = tid & 63, wave = tid >> 6;
  const int l15 = lane & 15, l4 = lane >> 4;
  const int wm = (wave >> 1) << 6, wn = (wave & 1) << 6;
  const int m0 = blockIdx.y << 7, n0 = blockIdx.x << 7;

  f32x4 acc[4][4];
#pragma unroll
  for (int i = 0; i < 4; ++i)
#pragma unroll
    for (int j = 0; j < 4; ++j) acc[i][j] = (f32x4){0.f, 0.f, 0.f, 0.f};

  const int lrow = lane >> 3;
  const int lcg = (lane & 7) ^ lrow;
  const u16* aG = A + (size_t)(m0 + wave * 8 + lrow) * lda + lcg * 8;
  const u16* bG = Bt + (size_t)(n0 + wave * 8 + lrow) * ldb + lcg * 8;
  u16* asDst = &As[(wave * 8) * 64];
  u16* bsDst = &Bs[(wave * 8) * 64];
  const int swz = (l15 & 7) << 3;

  for (int k0 = 0; k0 < K; k0 += 64) {
#pragma unroll
    for (int r = 0; r < 4; ++r) {
      GLD16(aG + (size_t)(r * 32) * lda + k0, asDst + r * 32 * 64);
      GLD16(bG + (size_t)(r * 32) * ldb + k0, bsDst + r * 32 * 64);
    }
    __syncthreads();
#pragma unroll
    for (int kk = 0; kk < 2; ++kk) {
      bf16x8 a[4], b[4];
      const int koff = (((kk << 2) + l4) << 3) ^ swz;
#pragma unroll
      for (int i = 0; i < 4; ++i) {
        a[i] = *(const bf16x8*)&As[(wm + (i << 4) + l15) * 64 + koff];
        b[i] = *(const bf16x8*)&Bs[(wn + (i << 4) + l15) * 64 + koff];
      }
#pragma unroll
      for (int i = 0; i < 4; ++i)
#pragma unroll
        for (int j = 0; j < 4; ++j)
          acc[i][j] = __builtin_amdgcn_mfma_f32_16x16x32_bf16(a[i], b[j], acc[i][j], 0, 0, 0);
    }
    __syncthreads();
  }

  const int f32m = flags[2];

  if (mode == 2 && n0 >= 2048) {        // V part -> transposed store into Vt
#pragma unroll
    for (int i = 0; i < 4; ++i) {
      const int rbase = m0 + wm + (i << 4) + l4 * 4;
#pragma unroll
      for (int j = 0; j < 4; ++j) {
        const int gn = n0 - 2048 + wn + (j << 4) + l15;
        ushort4 pk;
        pk.x = f2b(acc[i][j][0]); pk.y = f2b(acc[i][j][1]);
        pk.z = f2b(acc[i][j][2]); pk.w = f2b(acc[i][j][3]);
        *(ushort4*)&aux[(size_t)gn * 8192 + rbase] = pk;
      }
    }
    return;
  }

  // phase 1: transform in C-frag layout, bf16 into swizzled LDS
#pragma unroll
  for (int i = 0; i < 4; ++i) {
    const int rl0 = wm + (i << 4) + l4 * 4;
#pragma unroll
    for (int j = 0; j < 4; ++j) {
      const int cl = wn + (j << 4) + l15;
      float bv = 0.f;
      if (bias) bv = fl_at(bias, n0 + cl, f32m);
      const int chunk = cl >> 3, within = cl & 7;
#pragma unroll
      for (int r = 0; r < 4; ++r) {
        const int rl = rl0 + r;
        float v = acc[i][j][r] + bv;
        if (mode == 1) v = gelu_exact(v);
        const int wchunk = (chunk & 8) | ((chunk ^ rl) & 7);
        smem[rl * 128 + wchunk * 8 + within] = f2b(v);
      }
    }
  }
  __syncthreads();

  // phase 2: vectorized stores
  const int r = tid >> 1, h = tid & 1;
  const int grow = m0 + r;
#pragma unroll
  for (int cb = 0; cb < 8; ++cb) {
    const int chunkidx = h * 8 + cb;
    const int rchunk = (chunkidx & 8) | ((chunkidx ^ r) & 7);
    uint4 raw = *(const uint4*)&smem[r * 128 + rchunk * 8];
    *(uint4*)&C[(size_t)grow * ldc + n0 + chunkidx * 8] = raw;
  }
}

// --------------------------- fused dual score v2 ---------------------------
// W[m,n] = maskr?0:exp(sr*scale) + gamma*(maskf?0:exp(sf*scale)); row sums via
// shfl reduce + atomics. sr parked in packed-bf16 VGPRs between the two
// K-loops; mask bit-tiles in LDS; 36KB LDS total, 3 waves/SIMD.
__global__ __launch_bounds__(256, 3)
void score_fused(const u16* __restrict__ P,          // [8192][2048] Qr|Kr|Qf|Kf
                 const unsigned char* __restrict__ bmr,
                 const unsigned char* __restrict__ bmf,
                 u16* __restrict__ W, float* __restrict__ lvec) {
  __shared__ alignas(16) u16 stage[16384];            // 32 KB staging / w-tile
  __shared__ unsigned long long mrs[256], mfs[256];   // 4 KB mask bit-tiles
  const int tid = threadIdx.x;
  const int lane = tid & 63, wave = tid >> 6;
  const int l15 = lane & 15, l4 = lane >> 4;
  const int wm = (wave >> 1) << 6, wn = (wave & 1) << 6;
  const int m0 = blockIdx.y << 7, n0 = blockIdx.x << 7;

  {  // mask tiles -> LDS (ordering vs phase 2 covered by K-loop barriers)
    const int r = tid >> 1, hh = tid & 1;
    const size_t mo = (size_t)(m0 + r) * 1024 + (n0 >> 3) + hh * 8;
    mrs[tid] = *(const unsigned long long*)&bmr[mo];
    mfs[tid] = *(const unsigned long long*)&bmf[mo];
  }

  const int lrow = lane >> 3;
  const int lcg = (lane & 7) ^ lrow;
  const int swz = (l15 & 7) << 3;
  u16* asDst = &stage[(wave * 8) * 64];
  u16* bsDst = &stage[8192 + (wave * 8) * 64];

  unsigned int srp[4][4][2];   // packed bf16 sr*scale
  f32x4 acc[4][4];

  for (int p = 0; p < 2; ++p) {
#pragma unroll
    for (int i = 0; i < 4; ++i)
#pragma unroll
      for (int j = 0; j < 4; ++j) acc[i][j] = (f32x4){0.f, 0.f, 0.f, 0.f};

    const u16* aG = P + (p ? 1024 : 0) + (size_t)(m0 + wave * 8 + lrow) * 2048 + lcg * 8;
    const u16* bG = P + (p ? 1536 : 512) + (size_t)(n0 + wave * 8 + lrow) * 2048 + lcg * 8;

    for (int k0 = 0; k0 < 512; k0 += 64) {
#pragma unroll
      for (int r = 0; r < 4; ++r) {
        GLD16(aG + (size_t)(r * 32) * 2048 + k0, asDst + r * 32 * 64);
        GLD16(bG + (size_t)(r * 32) * 2048 + k0, bsDst + r * 32 * 64);
      }
      __syncthreads();
#pragma unroll
      for (int kk = 0; kk < 2; ++kk) {
        bf16x8 a[4], b[4];
        const int koff = (((kk << 2) + l4) << 3) ^ swz;
#pragma unroll
        for (int i = 0; i < 4; ++i) {
          a[i] = *(const bf16x8*)&stage[(wm + (i << 4) + l15) * 64 + koff];
          b[i] = *(const bf16x8*)&stage[8192 + (wn + (i << 4) + l15) * 64 + koff];
        }
#pragma unroll
        for (int i = 0; i < 4; ++i)
#pragma unroll
          for (int j = 0; j < 4; ++j)
            acc[i][j] = __builtin_amdgcn_mfma_f32_16x16x32_bf16(a[i], b[j], acc[i][j], 0, 0, 0);
      }
      __syncthreads();
    }

    if (p == 0) {   // park sr*scale as packed bf16
#pragma unroll
      for (int i = 0; i < 4; ++i)
#pragma unroll
        for (int j = 0; j < 4; ++j) {
          srp[i][j][0] = (unsigned int)f2b(acc[i][j][0] * SCALE_C)
                       | ((unsigned int)f2b(acc[i][j][1] * SCALE_C) << 16);
          srp[i][j][1] = (unsigned int)f2b(acc[i][j][2] * SCALE_C)
                       | ((unsigned int)f2b(acc[i][j][3] * SCALE_C) << 16);
        }
    }
  }

  // phase 2: w in C-frag layout; rowsum shfl-reduce; w -> stage (swizzled)
  const int hb = wn >> 6;
#pragma unroll
  for (int i = 0; i < 4; ++i) {
    const int rl0 = wm + (i << 4) + l4 * 4;
#pragma unroll
    for (int r = 0; r < 4; ++r) {
      const int rl = rl0 + r;
      const unsigned long long mr = mrs[rl * 2 + hb];
      const unsigned long long mf = mfs[rl * 2 + hb];
      float rsum = 0.f;
#pragma unroll
      for (int j = 0; j < 4; ++j) {
        const int cl = wn + (j << 4) + l15;
        const int bit = cl & 63;
        const float srv = b2f((u16)(srp[i][j][r >> 1] >> ((r & 1) * 16)));
        const float sfv = acc[i][j][r] * SCALE_C;
        const float wr = ((mr >> bit) & 1) ? 0.f : __expf(srv);
        const float wf = ((mf >> bit) & 1) ? 0.f : __expf(sfv);
        const float w = wr + GAMMA_C * wf;
        rsum += w;
        const int chunk = cl >> 3, within = cl & 7;
        const int wchunk = (chunk & 8) | ((chunk ^ rl) & 7);
        stage[rl * 128 + wchunk * 8 + within] = f2b(w);
      }
      rsum += __shfl_xor(rsum, 1);
      rsum += __shfl_xor(rsum, 2);
      rsum += __shfl_xor(rsum, 4);
      rsum += __shfl_xor(rsum, 8);
      if (l15 == 0) atomicAdd(&lvec[m0 + rl], rsum);
    }
  }
  __syncthreads();

  // phase 3: coalesced 16B stores
  const int rr = tid >> 1, hh = tid & 1;
  const int grow = m0 + rr;
#pragma unroll
  for (int cb = 0; cb < 8; ++cb) {
    const int chunkidx = hh * 8 + cb;
    const int rchunk = (chunkidx & 8) | ((chunkidx ^ rr) & 7);
    uint4 raw = *(const uint4*)&stage[rr * 128 + rchunk * 8];
    *(uint4*)&W[(size_t)grow * 8192 + n0 + chunkidx * 8] = raw;
  }
}

// ------------------------------ PV split-K ---------------------------------
// Oslab[z][8192][512] (f32) = W[128-tile] @ V over K-chunk z (plain stores).
__global__ __launch_bounds__(256)
void gemm_pv_splitk(const u16* __restrict__ W, const u16* __restrict__ Vt,
                    float* __restrict__ Oacc) {
  __shared__ alignas(16) u16 smem[16384];
  u16* As = smem;
  u16* Bs = smem + 8192;
  const int tid = threadIdx.x;
  const int lane = tid & 63, wave = tid >> 6;
  const int l15 = lane & 15, l4 = lane >> 4;
  const int wm = (wave >> 1) << 6, wn = (wave & 1) << 6;
  const int m0 = blockIdx.y << 7, n0 = blockIdx.x << 7;
  const int kbase = blockIdx.z << 11;
  float* Oslab = Oacc + (size_t)blockIdx.z * (8192 * 512);

  f32x4 acc[4][4];
#pragma unroll
  for (int i = 0; i < 4; ++i)
#pragma unroll
    for (int j = 0; j < 4; ++j) acc[i][j] = (f32x4){0.f, 0.f, 0.f, 0.f};

  const int lrow = lane >> 3;
  const int lcg = (lane & 7) ^ lrow;
  const u16* aG = W + (size_t)(m0 + wave * 8 + lrow) * 8192 + lcg * 8 + kbase;
  const u16* bG = Vt + (size_t)(n0 + wave * 8 + lrow) * 8192 + lcg * 8 + kbase;
  u16* asDst = &As[(wave * 8) * 64];
  u16* bsDst = &Bs[(wave * 8) * 64];
  const int swz = (l15 & 7) << 3;

  for (int k0 = 0; k0 < 2048; k0 += 64) {
#pragma unroll
    for (int r = 0; r < 4; ++r) {
      GLD16(aG + (size_t)(r * 32) * 8192 + k0, asDst + r * 32 * 64);
      GLD16(bG + (size_t)(r * 32) * 8192 + k0, bsDst + r * 32 * 64);
    }
    __syncthreads();
#pragma unroll
    for (int kk = 0; kk < 2; ++kk) {
      bf16x8 a[4], b[4];
      const int koff = (((kk << 2) + l4) << 3) ^ swz;
#pragma unroll
      for (int i = 0; i < 4; ++i) {
        a[i] = *(const bf16x8*)&As[(wm + (i << 4) + l15) * 64 + koff];
        b[i] = *(const bf16x8*)&Bs[(wn + (i << 4) + l15) * 64 + koff];
      }
#pragma unroll
      for (int i = 0; i < 4; ++i)
#pragma unroll
        for (int j = 0; j < 4; ++j)
          acc[i][j] = __builtin_amdgcn_mfma_f32_16x16x32_bf16(a[i], b[j], acc[i][j], 0, 0, 0);
    }
    __syncthreads();
  }

#pragma unroll
  for (int i = 0; i < 4; ++i) {
    const int rbase = m0 + wm + (i << 4) + l4 * 4;
#pragma unroll
    for (int j = 0; j < 4; ++j) {
      const int gn = n0 + wn + (j << 4) + l15;
#pragma unroll
      for (int r = 0; r < 4; ++r)
        Oslab[(size_t)(rbase + r) * 512 + gn] = acc[i][j][r];
    }
  }
}

// ------ fused: h = (sum of 4 O slabs)/lvec + residual; out = LN(h) ---------
__global__ __launch_bounds__(256)
void pv_ln(const float* __restrict__ Oacc, const float* __restrict__ lvec,
           const u16* __restrict__ res, const void* __restrict__ g,
           const void* __restrict__ be, u16* __restrict__ out,
           const int* __restrict__ flags) {
  const int row = blockIdx.x, tid = threadIdx.x;
  const int f32m = flags[2];
  const size_t off = (size_t)row * 512 + tid * 2;
  const size_t S = (size_t)8192 * 512;
  const float linv = 1.0f / lvec[row];
  const float o0 = Oacc[off] + Oacc[off + S] + Oacc[off + 2 * S] + Oacc[off + 3 * S];
  const float o1 = Oacc[off + 1] + Oacc[off + 1 + S] + Oacc[off + 1 + 2 * S] + Oacc[off + 1 + 3 * S];
  const float v0 = o0 * linv + b2f(res[off]);
  const float v1 = o1 * linv + b2f(res[off + 1]);
  __shared__ float r1[256], r2[256];
  r1[tid] = v0 + v1;
  r2[tid] = v0 * v0 + v1 * v1;
  __syncthreads();
  for (int s = 128; s > 0; s >>= 1) {
    if (tid < s) { r1[tid] += r1[tid + s]; r2[tid] += r2[tid + s]; }
    __syncthreads();
  }
  const float mu = r1[0] * (1.f / 512.f);
  const float var = r2[0] * (1.f / 512.f) - mu * mu;
  const float rs = rsqrtf(var + 1e-5f);
  out[off]     = f2b((v0 - mu) * rs * fl_at(g, tid * 2, f32m)     + fl_at(be, tid * 2, f32m));
  out[off + 1] = f2b((v1 - mu) * rs * fl_at(g, tid * 2 + 1, f32m) + fl_at(be, tid * 2 + 1, f32m));
}

// ------------------------------ residual + LN -------------------------------
__global__ __launch_bounds__(256)
void ln_fused(const u16* __restrict__ a, const u16* __restrict__ b,
              const void* __restrict__ g, const void* __restrict__ be,
              u16* __restrict__ out, const int* __restrict__ flags) {
  const int row = blockIdx.x, tid = threadIdx.x;
  const int f32m = flags[2];
  const size_t off = (size_t)row * 512 + tid * 2;
  const float v0 = b2f(a[off]) + b2f(b[off]);
  const float v1 = b2f(a[off + 1]) + b2f(b[off + 1]);
  __shared__ float r1[256], r2[256];
  r1[tid] = v0 + v1;
  r2[tid] = v0 * v0 + v1 * v1;
  __syncthreads();
  for (int s = 128; s > 0; s >>= 1) {
    if (tid < s) { r1[tid] += r1[tid + s]; r2[tid] += r2[tid + s]; }
    __syncthreads();
  }
  const float mu = r1[0] * (1.f / 512.f);
  const float var = r2[0] * (1.f / 512.f) - mu * mu;
  const float rs = rsqrtf(var + 1e-5f);
  out[off]     = f2b((v0 - mu) * rs * fl_at(g, tid * 2, f32m)     + fl_at(be, tid * 2, f32m));
  out[off + 1] = f2b((v1 - mu) * rs * fl_at(g, tid * 2 + 1, f32m) + fl_at(be, tid * 2 + 1, f32m));
}

// ------------------------------- host driver --------------------------------
extern "C" void kernel_launch(void* const* d_in, const int* in_sizes, int n_in,
                              void* d_out, int out_size, void* d_ws, size_t ws_size,
                              hipStream_t stream) {
  (void)in_sizes; (void)n_in; (void)out_size; (void)ws_size;
  const void* x = d_in[0];
  const void* dropidx = d_in[1];
  const void* rmask = d_in[2];
  const void* fmask = d_in[3];

  char* base = (char*)d_ws;
  size_t cur = 0;
  auto alloc = [&](size_t b) -> void* {
    void* p = base + cur;
    cur += (b + 255) & ~(size_t)255;
    return p;
  };

  int* flags = (int*)alloc(256);
  u16* Wt = (u16*)alloc((size_t)11 * 512 * 512 * 2);   // 10 QKV + head, transposed
  u16* wff1t = (u16*)alloc((size_t)2048 * 512 * 2);
  u16* wff2t = (u16*)alloc((size_t)512 * 2048 * 2);
  const size_t ND2 = (size_t)8192 * 512 * 2;
  u16* dropx = (u16*)alloc(ND2);
  u16* P = (u16*)alloc((size_t)8192 * 2048 * 2);       // Qr|Kr|Qf|Kf, ld 2048
  u16* Vt = (u16*)alloc(ND2);                          // V^T [512][8192]
  u16* H1 = (u16*)alloc(ND2);
  u16* H2 = (u16*)alloc(ND2);
  u16* FF2 = (u16*)alloc(ND2);
  u16* FF1 = (u16*)alloc((size_t)8192 * 2048 * 2);
  unsigned char* bmr = (unsigned char*)alloc((size_t)8192 * 1024);
  unsigned char* bmf = (unsigned char*)alloc((size_t)8192 * 1024);
  float* lvec = (float*)alloc((size_t)8192 * 4);
  float* Oacc = (float*)alloc((size_t)4 * 8192 * 512 * 4);   // 4 slabs
  u16* Wb = (u16*)alloc((size_t)8192 * 8192 * 2);      // score weights w

  detect_all<<<1, 256, 0, stream>>>((const unsigned char*)rmask, x, dropidx, flags);
  bitmask_prep<<<32768, 256, 0, stream>>>(rmask, fmask, bmr, bmf, flags);

  const dim3 tb(32, 8);
  PtrPack wp;
  for (int i = 0; i < 5; ++i) wp.p[i] = d_in[4 + i];       // enc
  for (int i = 0; i < 5; ++i) wp.p[5 + i] = d_in[9 + i];   // dec
  wp.p[10] = d_in[24];                                      // head
  transpose_cvt_b<<<dim3(16, 16, 11), tb, 0, stream>>>(wp, Wt, flags);
  transpose_cvt<<<dim3(64, 16), tb, 0, stream>>>(d_in[14], wff1t, 512, 2048, flags);
  transpose_cvt<<<dim3(16, 64), tb, 0, stream>>>(d_in[16], wff2t, 2048, 512, flags);

  cvt_to_bf16<<<(8192 * 512 + 255) / 256, 256, 0, stream>>>(x, dropx, 8192 * 512, flags);
  zero_drop<<<(NG + 255) / 256, 256, 0, stream>>>(dropx, dropidx, flags);

  auto gemm = [&](const u16* A, int lda, const u16* Bt, int ldb, u16* Cc, int ldc,
                  int M, int Nn, int K, int mode, const void* bias, u16* aux) {
    gemm_bt<<<dim3(Nn / 128, M / 128), 256, 0, stream>>>(
        A, lda, Bt, ldb, Cc, ldc, K, mode, bias, flags, aux);
  };

  auto attention = [&](const u16* Hin, const u16* Wqkv, const void* lnG,
                       const void* lnB, u16* outLN) {
    zero_f32<<<32, 256, 0, stream>>>(lvec, 8192);
    gemm(Hin, 512, Wqkv, 512, P, 2048, 8192, 2560, 512, 2, nullptr, Vt);
    score_fused<<<dim3(64, 64), 256, 0, stream>>>(P, bmr, bmf, Wb, lvec);
    gemm_pv_splitk<<<dim3(4, 64, 4), 256, 0, stream>>>(Wb, Vt, Oacc);
    pv_ln<<<8192, 256, 0, stream>>>(Oacc, lvec, Hin, lnG, lnB, outLN, flags);
  };

  // encoder
  attention(dropx, Wt, d_in[18], d_in[19], H1);
  gemm(H1, 512, wff1t, 512, FF1, 2048, 8192, 2048, 512, 1, d_in[15], nullptr);
  gemm(FF1, 2048, wff2t, 2048, FF2, 512, 8192, 512, 2048, 0, d_in[17], nullptr);
  ln_fused<<<8192, 256, 0, stream>>>(H1, FF2, d_in[20], d_in[21], H2, flags);
  // decoder
  attention(H2, Wt + (size_t)5 * 512 * 512, d_in[22], d_in[23], H1);
  gemm(H1, 512, Wt + (size_t)10 * 512 * 512, 512, FF2, 512, 8192, 512, 512, 0,
       d_in[25], nullptr);
  gather_out_k<<<(NG + 255) / 256, 256, 0, stream>>>(x, FF2, dropidx, d_out, flags);
}